// Round 18
// baseline (975.176 us; speedup 1.0000x reference)
//
#include <hip/hip_runtime.h>
#include <hip/hip_bf16.h>
#include <math.h>

#define NB 32
#define CH 16
#define N1 127
#define G 256
#define GG (G*G)

typedef float v2f __attribute__((ext_vector_type(2)));

// acc(lo=Re,hi=Im) += complex(x) * complex(w);  x=(xr,xi), w=(wr,wi)
#define CFMA(acc, x, w) do { \
  asm("v_pk_fma_f32 %0, %1, %2, %0 op_sel:[0,0,0] op_sel_hi:[0,1,1]" \
      : "+v"(acc) : "v"(x), "v"(w)); \
  asm("v_pk_fma_f32 %0, %1, %2, %0 op_sel:[1,1,0] op_sel_hi:[1,0,1] neg_lo:[0,1,0]" \
      : "+v"(acc) : "v"(x), "v"(w)); \
} while (0)
// acc += complex(x) * conj(t);  t=(c,s):  re += xr c + xi s;  im += xi c - xr s
#define CFMA_CONJ(acc, x, t) do { \
  asm("v_pk_fma_f32 %0, %1, %2, %0 op_sel:[0,0,0] op_sel_hi:[1,0,1]" \
      : "+v"(acc) : "v"(x), "v"(t)); \
  asm("v_pk_fma_f32 %0, %1, %2, %0 op_sel:[1,1,0] op_sel_hi:[0,1,1] neg_hi:[0,1,0]" \
      : "+v"(acc) : "v"(x), "v"(t)); \
} while (0)
// acc += real(x.lo) * complex(w)
#define RFMA_LO(acc, x, w) \
  asm("v_pk_fma_f32 %0, %1, %2, %0 op_sel:[0,0,0] op_sel_hi:[0,1,1]" \
      : "+v"(acc) : "v"(x), "v"(w))
// acc += real(x.hi) * complex(w)
#define RFMA_HI(acc, x, w) \
  asm("v_pk_fma_f32 %0, %1, %2, %0 op_sel:[1,0,0] op_sel_hi:[1,1,1]" \
      : "+v"(acc) : "v"(x), "v"(w))

// ---------------------------------------------------------------------------
__global__ void init_sintab(float* __restrict__ sintab) {
    int t = threadIdx.x;
    sintab[t] = sinf(6.28318530717958647692f * (float)t / 256.0f);
}

// adj(w)[b,a,c,ky,kx] = conj(w[b,c,a,kx,ky])
__global__ __launch_bounds__(256) void prep_adj16(
    const float* __restrict__ wr, const float* __restrict__ wi,
    float* __restrict__ our, float* __restrict__ oui) {
    int idx = blockIdx.x * 256 + threadIdx.x;
    if (idx >= NB*CH*CH*9) return;
    int tap = idx % 9; int t = idx / 9;
    int c = t % CH; t /= CH;
    int a = t % CH; int b = t / CH;
    int ky = tap / 3, kx = tap % 3;
    int src = ((b*CH + c)*CH + a)*9 + kx*3 + ky;
    our[idx] = wr[src];
    oui[idx] = -wi[src];
}

__global__ __launch_bounds__(256) void prep_adj1(
    const float* __restrict__ wr, const float* __restrict__ wi,
    float* __restrict__ our, float* __restrict__ oui) {
    int idx = blockIdx.x * 256 + threadIdx.x;
    if (idx >= NB*CH*9) return;
    int tap = idx % 9; int t = idx / 9;
    int c = t % CH; int b = t / CH;
    int ky = tap / 3, kx = tap % 3;
    int src = (b*CH + c)*9 + kx*3 + ky;
    our[idx] = wr[src];
    oui[idx] = -wi[src];
}

// ---------------------------------------------------------------------------
// Kernel-tap composition: R[t] = sum_{a+b=t} P[a] Q[b]  (complex), contract CM
template<int CO, int CM, int CI, int KP, int KQ>
__global__ __launch_bounds__(256) void compose_k(
    const float* __restrict__ Pr, const float* __restrict__ Pi,
    const float* __restrict__ Qr, const float* __restrict__ Qi,
    float* __restrict__ Rr, float* __restrict__ Ri) {
    constexpr int T = KP + KQ - 1;
    int idx = blockIdx.x * 256 + threadIdx.x;
    if (idx >= NB*CO*CI*T*T) return;
    int txp = idx % T; int t = idx / T;
    int typ = t % T; t /= T;
    int ci = t % CI; t /= CI;
    int co = t % CO; int b = t / CO;
    float ar = 0.f, ai = 0.f;
    for (int m = 0; m < CM; ++m) {
        const float* pr = Pr + (((size_t)b*CO + co)*CM + m)*KP*KP;
        const float* pi = Pi + (((size_t)b*CO + co)*CM + m)*KP*KP;
        const float* qr = Qr + (((size_t)b*CM + m)*CI + ci)*KQ*KQ;
        const float* qi = Qi + (((size_t)b*CM + m)*CI + ci)*KQ*KQ;
        for (int ay = 0; ay < KP; ++ay) {
            int by = typ - ay; if (by < 0 || by >= KQ) continue;
            for (int ax = 0; ax < KP; ++ax) {
                int bx = txp - ax; if (bx < 0 || bx >= KQ) continue;
                float prr = pr[ay*KP+ax], pii = pi[ay*KP+ax];
                float qrr = qr[by*KQ+bx], qii = qi[by*KQ+bx];
                ar += prr*qrr - pii*qii;
                ai += prr*qii + pii*qrr;
            }
        }
    }
    Rr[idx] = ar; Ri[idx] = ai;
}

// ---------------------------------------------------------------------------
// DST stage 1  ((-1)^K folded into sin index)
__global__ __launch_bounds__(256) void dst_stage1(
    const float* __restrict__ r, const float* __restrict__ sintab,
    float* __restrict__ T1, int nb) {
    __shared__ float ss[256];
    ss[threadIdx.x] = sintab[threadIdx.x];
    __syncthreads();
    int idx = blockIdx.x * 256 + threadIdx.x;
    if (idx >= nb*G*N1) return;
    int kk = idx % N1;
    int t = idx / N1;
    int j1 = t & 255; int b = t >> 8;
    const float* rb = r + b * N1 * N1;
    const int j1s = (j1 + 128) & 255;
    float acc = 0.f;
    for (int K = 1; K <= N1; ++K) {
        acc = fmaf(ss[(j1s * K) & 255], rb[(K - 1) * N1 + kk], acc);
    }
    T1[idx] = acc;
}

// DST stage 2
__global__ __launch_bounds__(256) void dst_stage2(
    const float* __restrict__ T1, const float* __restrict__ sintab,
    float* __restrict__ rhat) {
    __shared__ float ss[256];
    ss[threadIdx.x] = sintab[threadIdx.x];
    __syncthreads();
    int idx = blockIdx.x * 256 + threadIdx.x;
    int j2 = idx & 255;
    int t = idx >> 8;
    int j1 = t & 255; int b = t >> 8;
    const float* t1 = T1 + ((size_t)b * G + j1) * N1;
    const int j2s = (j2 + 128) & 255;
    float acc = 0.f;
    for (int kk = 0; kk < N1; ++kk) {
        acc = fmaf(ss[(j2s * (kk + 1)) & 255], t1[kk], acc);
    }
    rhat[idx] = acc * (-4.0f / 65536.0f);
}

// ---------------------------------------------------------------------------
// FUSED conv kernel (round-17 structure + theta register prefetch 1 ci ahead):
// per 32x32 HC tile, compute composed fwd A on the fly from a 44x44 rhat halo,
// patch border from CAc, theta-multiply into single sTA buffer, accumulate
// composed adjoint 7x7. Theta for ci+1 is loaded into registers at the start
// of iteration ci -> load-consume distance ~ A+write+adj+A (fully hidden).
__global__ __launch_bounds__(256) void fused7_kernel(
    const float* __restrict__ rhat,
    const float* __restrict__ tr, const float* __restrict__ ti,   // [b][16][GG]
    const float* __restrict__ w7fr, const float* __restrict__ w7fi, // [b][16][49]
    const float* __restrict__ w7ar, const float* __restrict__ w7ai, // [b][16][49]
    const float* __restrict__ CAc,  // [b][16][4][2][256][2] corrected A band
    float* __restrict__ HCc, float* __restrict__ PTA, int cb) {
    __shared__ float sR[44*44];        // rhat halo, stride 44 (176B rows, 16B aligned)
    __shared__ float sTA[38*38*2];     // theta*A staged (single buffer)
    __shared__ float sWf[16*49*2];
    __shared__ float sWa[16*49*2];
    const int lin = blockIdx.x;        // 64*cb blocks
    const int swz = (lin & 7) * (8 * cb) + (lin >> 3);
    const int b = swz >> 6;
    const int tile = swz & 63;
    const int x0 = (tile & 7) * 32;
    const int y0 = (tile >> 3) * 32;
    const int tid = threadIdx.x;
    const bool border = (x0 == 0) | (x0 == 224) | (y0 == 0) | (y0 == 224);
    {
        const float* fr = w7fr + (size_t)b*784; const float* fi = w7fi + (size_t)b*784;
        const float* ar = w7ar + (size_t)b*784; const float* ai = w7ai + (size_t)b*784;
        for (int t = tid; t < 784; t += 256) {
            sWf[2*t] = fr[t]; sWf[2*t+1] = fi[t];
            sWa[2*t] = ar[t]; sWa[2*t+1] = ai[t];
        }
    }
    {
        const float* rb = rhat + (size_t)b * GG;
        for (int t = tid; t < 44*44; t += 256) {
            int ry = t / 44, rx = t - ry*44;
            int gy = y0 - 6 + ry, gx = x0 - 6 + rx;
            bool ok = ((unsigned)gy < G) & ((unsigned)gx < G);
            sR[ry*44 + rx] = ok ? rb[gy*G + gx] : 0.f;
        }
    }
    // A-phase mapping: 190 active threads, each owns 8 consecutive A-halo px
    const bool act = tid < 190;
    const int arow = act ? (tid % 38) : 0;   // A-halo row 0..37
    const int cg   = act ? (tid / 38) : 0;   // col group (8 px)
    const int pgy  = y0 - 3 + arow;
    // adj mapping: thread owns 4 consecutive outputs in one row
    const int ty = tid >> 3, txi = tid & 7;
    v2f hacc[4];
#pragma unroll
    for (int k = 0; k < 4; ++k) hacc[k] = (v2f){0.f, 0.f};
    const size_t planeT = (size_t)b * 16 * GG;

    // theta register-load for channel cidx
    auto loadTheta = [&](int cidx, float (&otr)[8], float (&oti)[8]) {
        if (!act) return;
        const float* trc = tr + planeT + (size_t)cidx * GG;
        const float* tic = ti + planeT + (size_t)cidx * GG;
#pragma unroll
        for (int k = 0; k < 8; ++k) {
            int acol = 8*cg + k;
            int pgx = x0 - 3 + acol;
            bool ok = (acol < 38) & ((unsigned)pgy < G) & ((unsigned)pgx < G);
            otr[k] = ok ? trc[pgy*G + pgx] : 0.f;
            oti[k] = ok ? tic[pgy*G + pgx] : 0.f;
        }
    };

    // one ci iteration: prefetch theta(ci+1) into nxt, use cur for the write
    auto body = [&](int ci, float (&curR)[8], float (&curI)[8],
                    float (&nxtR)[8], float (&nxtI)[8]) {
        if (ci + 1 < 16) loadTheta(ci + 1, nxtR, nxtI);
        // ---- A-halo compute (composed fwd 7x7, real input, pk fma) -------
        v2f aa[8];
#pragma unroll
        for (int k = 0; k < 8; ++k) aa[k] = (v2f){0.f, 0.f};
        if (act) {
            const float* wci = &sWf[ci*49*2];
#pragma unroll
            for (int dy = 0; dy < 7; ++dy) {
                const float* rp = &sR[(arow + dy)*44 + 8*cg];
                v2f fv[8];
#pragma unroll
                for (int q = 0; q < 4; ++q) {
                    const float4 vv = *reinterpret_cast<const float4*>(&rp[4*q]);
                    fv[2*q]   = (v2f){vv.x, vv.y};
                    fv[2*q+1] = (v2f){vv.z, vv.w};
                }
#pragma unroll
                for (int dx = 0; dx < 7; ++dx) {
                    const v2f wv = *reinterpret_cast<const v2f*>(&wci[(dy*7+dx)*2]);
                    const int h = dx >> 1;
                    if ((dx & 1) == 0) {
#pragma unroll
                        for (int m = 0; m < 4; ++m) {
                            RFMA_LO(aa[2*m],   fv[h+m], wv);
                            RFMA_HI(aa[2*m+1], fv[h+m], wv);
                        }
                    } else {
#pragma unroll
                        for (int m = 0; m < 4; ++m) {
                            RFMA_HI(aa[2*m],   fv[h+m],   wv);
                            RFMA_LO(aa[2*m+1], fv[h+m+1], wv);
                        }
                    }
                }
            }
            // patch 2-px border band with corrected A from strip chain
            if (border) {
#pragma unroll
                for (int k = 0; k < 8; ++k) {
                    int acol = 8*cg + k;
                    int gx = x0 - 3 + acol;
                    if (acol < 38 && (unsigned)pgy < G && (unsigned)gx < G) {
                        int s = -1, uu = 0, vv = 0;
                        if (pgy < 2)        { s = 0; uu = pgy;       vv = gx;  }
                        else if (pgy >= 254){ s = 1; uu = pgy - 254; vv = gx;  }
                        else if (gx < 2)    { s = 2; uu = gx;        vv = pgy; }
                        else if (gx >= 254) { s = 3; uu = gx - 254;  vv = pgy; }
                        if (s >= 0) {
                            size_t o = ((((size_t)b*16 + ci)*4 + s)*2 + uu)*256 + vv;
                            aa[k] = *reinterpret_cast<const v2f*>(&CAc[o*2]);
                        }
                    }
                }
            }
        }
        __syncthreads();   // all waves done reading sTA for ci-1
        // ---- theta*A -> sTA (+ PTA extraction on border tiles) -----------
        if (act) {
#pragma unroll
            for (int k = 0; k < 8; ++k) {
                int acol = 8*cg + k;
                if (acol < 38) {
                    float hr = fmaf(aa[k].x, curR[k], -aa[k].y*curI[k]);
                    float hi = fmaf(aa[k].x, curI[k],  aa[k].y*curR[k]);
                    *reinterpret_cast<v2f*>(&sTA[(arow*38 + acol)*2]) = (v2f){hr, hi};
                    if (border) {
                        int gx = x0 - 3 + acol;
                        if ((unsigned)pgy < G && (unsigned)gx < G) {
                            const size_t cbase = ((size_t)b*16 + ci) * 4;
                            if (pgy < 5)    { size_t o = ((cbase+0)*5 + pgy      )*256 + gx;  *reinterpret_cast<v2f*>(&PTA[2*o]) = (v2f){hr,hi}; }
                            if (pgy >= 251) { size_t o = ((cbase+1)*5 + pgy - 251)*256 + gx;  *reinterpret_cast<v2f*>(&PTA[2*o]) = (v2f){hr,hi}; }
                            if (gx < 5)     { size_t o = ((cbase+2)*5 + gx       )*256 + pgy; *reinterpret_cast<v2f*>(&PTA[2*o]) = (v2f){hr,hi}; }
                            if (gx >= 251)  { size_t o = ((cbase+3)*5 + gx - 251 )*256 + pgy; *reinterpret_cast<v2f*>(&PTA[2*o]) = (v2f){hr,hi}; }
                        }
                    }
                }
            }
        }
        __syncthreads();   // sTA ready
        // ---- adjoint accumulate ------------------------------------------
        {
            const float* wci = &sWa[ci*49*2];
#pragma unroll
            for (int dy = 0; dy < 7; ++dy) {
                const float* rowp = &sTA[((ty + dy)*38 + txi*4)*2];
                v2f win[10];
#pragma unroll
                for (int q = 0; q < 5; ++q) {
                    const float4 vv = *reinterpret_cast<const float4*>(&rowp[q*4]);
                    win[2*q]   = (v2f){vv.x, vv.y};
                    win[2*q+1] = (v2f){vv.z, vv.w};
                }
#pragma unroll
                for (int dx = 0; dx < 7; ++dx) {
                    const v2f wv = *reinterpret_cast<const v2f*>(&wci[(dy*7+dx)*2]);
#pragma unroll
                    for (int k = 0; k < 4; ++k)
                        CFMA(hacc[k], win[k+dx], wv);
                }
            }
        }
    };

    float thrA[8], thiA[8], thrB[8], thiB[8];
    loadTheta(0, thrA, thiA);
    __syncthreads();            // sR / sW staged
#pragma unroll 1
    for (int ci = 0; ci < 16; ci += 2) {
        body(ci,     thrA, thiA, thrB, thiB);
        body(ci + 1, thrB, thiB, thrA, thiA);
    }

    const size_t outB = (size_t)b * GG;
    const int oy = y0 + ty, ox = x0 + txi*4;
    float4 o0 = make_float4(hacc[0].x, hacc[0].y, hacc[1].x, hacc[1].y);
    float4 o1 = make_float4(hacc[2].x, hacc[2].y, hacc[3].x, hacc[3].y);
    *reinterpret_cast<float4*>(&HCc[(outB + oy*G + ox)*2])     = o0;
    *reinterpret_cast<float4*>(&HCc[(outB + oy*G + ox)*2 + 4]) = o1;
}

// ---------------------------------------------------------------------------
// Strip machinery. strip s: 0=TOP, 1=BOT, 2=LEF, 3=RIG. [b][ch][s][u:4][v:256].
__device__ __forceinline__ size_t sidx(int b, int ch, int s, int u, int v) {
    return ((((size_t)b*CH + ch)*4 + s)*4 + u)*256 + v;
}
__device__ __forceinline__ void spos(int s, int u, int v, int& y, int& x) {
    y = (s == 0) ? u : (s == 1) ? 252 + u : v;
    x = (s == 2) ? u : (s == 3) ? 252 + u : v;
}

// stage 1 fwd: conv1 (w1, 1->16, real rhat) exact, all u in [0,4)
__global__ __launch_bounds__(256) void strip_fwd1(
    const float* __restrict__ rhat,
    const float* __restrict__ w1r_, const float* __restrict__ w1i_, // [b][16][9]
    float* __restrict__ S1r, float* __restrict__ S1i) {
    __shared__ float sW[16*9*2];
    const int s = blockIdx.x, b = blockIdx.y;
    for (int t = threadIdx.x; t < 144; t += 256) {
        sW[2*t] = w1r_[(size_t)b*144 + t]; sW[2*t+1] = w1i_[(size_t)b*144 + t];
    }
    __syncthreads();
    const int v = threadIdx.x;
    const float* rb = rhat + (size_t)b * GG;
    for (int u = 0; u < 4; ++u) {
        int y, x; spos(s, u, v, y, x);
        float xv[9];
#pragma unroll
        for (int dy = -1; dy <= 1; ++dy)
#pragma unroll
            for (int dx = -1; dx <= 1; ++dx) {
                int gy = y + dy, gx = x + dx;
                bool ok = ((unsigned)gy < G) & ((unsigned)gx < G);
                xv[(dy+1)*3 + dx+1] = ok ? rb[gy*G+gx] : 0.f;
            }
#pragma unroll
        for (int co = 0; co < 16; ++co) {
            float ar = 0.f, ai = 0.f;
#pragma unroll
            for (int tap = 0; tap < 9; ++tap) {
                ar = fmaf(xv[tap], sW[(co*9+tap)*2], ar);
                ai = fmaf(xv[tap], sW[(co*9+tap)*2+1], ai);
            }
            S1r[sidx(b, co, s, u, v)] = ar;
            S1i[sidx(b, co, s, u, v)] = ai;
        }
    }
}

// stage 1 adj (packed): a3-conv on packed theta.*A bands. u in [0,4). pk_fma.
__global__ __launch_bounds__(256) void strip_adj1_packed(
    const float* __restrict__ PTA,   // [b][ci][4][5][256][2]
    const float* __restrict__ wr_, const float* __restrict__ wi_, // [b][16][16][9]
    float* __restrict__ S1r, float* __restrict__ S1i) {
    __shared__ float sW[16*16*9*2];
    const int s = blockIdx.x >> 2, vt = blockIdx.x & 3, b = blockIdx.y;
    for (int t = threadIdx.x; t < 2304; t += 256) {
        sW[2*t] = wr_[(size_t)b*2304 + t]; sW[2*t+1] = wi_[(size_t)b*2304 + t];
    }
    __syncthreads();
    const int v = vt * 64 + (threadIdx.x & 63);
    const int u = threadIdx.x >> 6;           // 0..3
    const int off = (s == 1 || s == 3) ? 1 : 0;
    v2f acc[16];
#pragma unroll
    for (int co = 0; co < 16; ++co) acc[co] = (v2f){0.f, 0.f};
    for (int ci = 0; ci < 16; ++ci) {
        const float* base = PTA + ((((size_t)b*16 + ci)*4 + s)*5) * 512;
        v2f n2[9];
#pragma unroll
        for (int dy = -1; dy <= 1; ++dy)
#pragma unroll
            for (int dx = -1; dx <= 1; ++dx) {
                int pu = (s < 2) ? (u + off + dy) : (u + off + dx);
                int vp = (s < 2) ? (v + dx) : (v + dy);
                v2f val = (v2f){0.f, 0.f};
                if (((unsigned)pu < 5u) & ((unsigned)vp < 256u))
                    val = *reinterpret_cast<const v2f*>(&base[(pu*256 + vp)*2]);
                n2[(dy+1)*3+dx+1] = val;
            }
#pragma unroll
        for (int co = 0; co < 16; ++co)
#pragma unroll
            for (int tap = 0; tap < 9; ++tap) {
                const v2f wv = *reinterpret_cast<const v2f*>(&sW[((co*16+ci)*9+tap)*2]);
                CFMA(acc[co], n2[tap], wv);
            }
    }
#pragma unroll
    for (int co = 0; co < 16; ++co) {
        S1r[sidx(b, co, s, u, v)] = acc[co].x;
        S1i[sidx(b, co, s, u, v)] = acc[co].y;
    }
}

// stage 2: 16->16 conv strips->strips, u in [u0, u0+3). grid (16, cb). pk_fma.
__global__ __launch_bounds__(256) void strip_mid(
    const float* __restrict__ Ar, const float* __restrict__ Ai,
    const float* __restrict__ wr_, const float* __restrict__ wi_, // [b][16][16][9]
    float* __restrict__ Br, float* __restrict__ Bi) {
    __shared__ float sW[16*16*9*2];
    const int s = blockIdx.x >> 2, vt = blockIdx.x & 3, b = blockIdx.y;
    for (int t = threadIdx.x; t < 2304; t += 256) {
        sW[2*t] = wr_[(size_t)b*2304 + t]; sW[2*t+1] = wi_[(size_t)b*2304 + t];
    }
    __syncthreads();
    const int v = vt * 64 + (threadIdx.x & 63);
    const int uslot = threadIdx.x >> 6;
    if (uslot >= 3) return;
    const int u0 = (s == 1 || s == 3) ? 1 : 0;
    const int u = u0 + uslot;
    int y, x; spos(s, u, v, y, x);
    v2f acc[16];
#pragma unroll
    for (int co = 0; co < 16; ++co) acc[co] = (v2f){0.f, 0.f};
    for (int ci = 0; ci < 16; ++ci) {
        v2f n2[9];
#pragma unroll
        for (int dy = -1; dy <= 1; ++dy)
#pragma unroll
            for (int dx = -1; dx <= 1; ++dx) {
                int gy = y + dy, gx = x + dx;
                v2f val = (v2f){0.f, 0.f};
                if (((unsigned)gy < G) & ((unsigned)gx < G)) {
                    int up = (s < 2) ? u + dy : u + dx;
                    int vp = (s < 2) ? v + dx : v + dy;
                    size_t ix = sidx(b, ci, s, up, vp);
                    val.x = Ar[ix]; val.y = Ai[ix];
                }
                n2[(dy+1)*3+dx+1] = val;
            }
#pragma unroll
        for (int co = 0; co < 16; ++co)
#pragma unroll
            for (int tap = 0; tap < 9; ++tap) {
                const v2f wv = *reinterpret_cast<const v2f*>(&sW[((co*16+ci)*9+tap)*2]);
                CFMA(acc[co], n2[tap], wv);
            }
    }
#pragma unroll
    for (int co = 0; co < 16; ++co) {
        Br[sidx(b, co, s, u, v)] = acc[co].x;
        Bi[sidx(b, co, s, u, v)] = acc[co].y;
    }
}

// stage 3 fwd variant: 16 ch from strips -> compact corrected-A band CAc.
__global__ __launch_bounds__(256) void strip_fin_ca(
    const float* __restrict__ Ar, const float* __restrict__ Ai,
    const float* __restrict__ wr_, const float* __restrict__ wi_, // [b][16][16][9]
    float* __restrict__ CAc) {
    __shared__ float sW[16*16*9*2];
    const int s = blockIdx.x >> 2, vt = blockIdx.x & 3, b = blockIdx.y;
    for (int t = threadIdx.x; t < 2304; t += 256) {
        sW[2*t] = wr_[(size_t)b*2304 + t]; sW[2*t+1] = wi_[(size_t)b*2304 + t];
    }
    __syncthreads();
    const int v = vt * 64 + (threadIdx.x & 63);
    const int uslot = threadIdx.x >> 6;
    if (uslot >= 2) return;
    const int u0 = (s == 1 || s == 3) ? 2 : 0;
    const int u = u0 + uslot;
    int y, x; spos(s, u, v, y, x);
    v2f acc[16];
#pragma unroll
    for (int co = 0; co < 16; ++co) acc[co] = (v2f){0.f, 0.f};
    for (int ci = 0; ci < 16; ++ci) {
        v2f n2[9];
#pragma unroll
        for (int dy = -1; dy <= 1; ++dy)
#pragma unroll
            for (int dx = -1; dx <= 1; ++dx) {
                int gy = y + dy, gx = x + dx;
                v2f val = (v2f){0.f, 0.f};
                if (((unsigned)gy < G) & ((unsigned)gx < G)) {
                    int up = (s < 2) ? u + dy : u + dx;
                    int vp = (s < 2) ? v + dx : v + dy;
                    size_t ix = sidx(b, ci, s, up, vp);
                    val.x = Ar[ix]; val.y = Ai[ix];
                }
                n2[(dy+1)*3+dx+1] = val;
            }
#pragma unroll
        for (int co = 0; co < 16; ++co)
#pragma unroll
            for (int tap = 0; tap < 9; ++tap) {
                const v2f wv = *reinterpret_cast<const v2f*>(&sW[((co*16+ci)*9+tap)*2]);
                CFMA(acc[co], n2[tap], wv);
            }
    }
#pragma unroll
    for (int co = 0; co < 16; ++co) {
        size_t o = ((((size_t)b*16 + co)*4 + s)*2 + uslot)*256 + v;
        *reinterpret_cast<v2f*>(&CAc[o*2]) = acc[co];
    }
}

// stage 3 adj: 1 ch from strips -> overwrite band in interleaved HCc.
__global__ __launch_bounds__(256) void strip_fin1(
    const float* __restrict__ Ar, const float* __restrict__ Ai,
    const float* __restrict__ wr_, const float* __restrict__ wi_, // [b][1][16][9]
    float* __restrict__ Oc) {
    __shared__ float sW[16*9*2];
    const int s = blockIdx.x >> 2, vt = blockIdx.x & 3, b = blockIdx.y;
    for (int t = threadIdx.x; t < 144; t += 256) {
        sW[2*t] = wr_[(size_t)b*144 + t]; sW[2*t+1] = wi_[(size_t)b*144 + t];
    }
    __syncthreads();
    const int v = vt * 64 + (threadIdx.x & 63);
    const int uslot = threadIdx.x >> 6;
    if (uslot >= 2) return;
    const int u0 = (s == 1 || s == 3) ? 2 : 0;
    const int u = u0 + uslot;
    int y, x; spos(s, u, v, y, x);
    v2f acc = (v2f){0.f, 0.f};
    for (int ci = 0; ci < 16; ++ci) {
#pragma unroll
        for (int dy = -1; dy <= 1; ++dy)
#pragma unroll
            for (int dx = -1; dx <= 1; ++dx) {
                int gy = y + dy, gx = x + dx;
                v2f val = (v2f){0.f, 0.f};
                if (((unsigned)gy < G) & ((unsigned)gx < G)) {
                    int up = (s < 2) ? u + dy : u + dx;
                    int vp = (s < 2) ? v + dx : v + dy;
                    size_t ix = sidx(b, ci, s, up, vp);
                    val.x = Ar[ix]; val.y = Ai[ix];
                }
                const v2f wv = *reinterpret_cast<const v2f*>(&sW[(ci*9 + (dy+1)*3 + dx+1)*2]);
                CFMA(acc, val, wv);
            }
    }
    *reinterpret_cast<v2f*>(&Oc[(((size_t)b)*GG + y*G + x)*2]) = acc;
}

// ---------------------------------------------------------------------------
// FFT stage 1 (tiled GEMM): U[b][k1][j2] = sum_j1 HC[b][j1][j2] e^{-2pi i k1 j1/256}.
__global__ __launch_bounds__(256) void fft_stage1(
    const float* __restrict__ HCc, const float* __restrict__ sintab,
    float* __restrict__ Uc) {
    __shared__ v2f sHC[64][16];
    __shared__ v2f sTW[256];
    const int jt = blockIdx.x & 15;
    const int b  = blockIdx.x >> 4;
    const int tid = threadIdx.x;
    {
        int ph = tid;
        sTW[tid] = (v2f){sintab[(ph + 64) & 255], sintab[ph]};  // (c, s)
    }
    const int j2c = tid & 15;
    const int kg  = tid >> 4;           // 0..15
    const int j2  = jt * 16 + j2c;
    const float* hc = HCc + ((size_t)b * GG + j2) * 2;
    v2f acc[8];
    int ph[8];
#pragma unroll
    for (int i = 0; i < 8; ++i) { acc[i] = (v2f){0.f, 0.f}; ph[i] = 0; }
    for (int c = 0; c < 4; ++c) {
        __syncthreads();
#pragma unroll
        for (int q = 0; q < 4; ++q) {
            int jj = 16*q + kg;
            sHC[jj][j2c] = *reinterpret_cast<const v2f*>(&hc[((size_t)(c*64 + jj) * G) * 2]);
        }
        __syncthreads();
#pragma unroll 8
        for (int jj = 0; jj < 64; ++jj) {
            const v2f x = sHC[jj][j2c];
#pragma unroll
            for (int i = 0; i < 8; ++i) {
                const v2f t = sTW[ph[i]];
                CFMA_CONJ(acc[i], x, t);
                ph[i] = (ph[i] + kg + 16*i) & 255;
            }
        }
    }
#pragma unroll
    for (int i = 0; i < 8; ++i) {
        int k1 = kg + 16*i;
        if (k1 < N1)
            *reinterpret_cast<v2f*>(&Uc[(((size_t)b * N1 + k1) * G + j2) * 2]) = acc[i];
    }
}

// FFT stage 2: e[b][k1][k2] = (-1)^{k1+k2} Re( sum_j2 U[..] e^{-2pi i k2 j2/256} ).
__global__ __launch_bounds__(128) void fft_stage2(
    const float* __restrict__ Uc, const float* __restrict__ sintab,
    float* __restrict__ out) {
    __shared__ v2f sU[256];
    __shared__ float ss[256];
    const int k1 = blockIdx.x % N1;
    const int b  = blockIdx.x / N1;
    const int tid = threadIdx.x;
    const float* uc = Uc + ((size_t)b * N1 + k1) * G * 2;
    sU[tid]       = *reinterpret_cast<const v2f*>(&uc[tid * 2]);
    sU[tid + 128] = *reinterpret_cast<const v2f*>(&uc[(tid + 128) * 2]);
    ss[tid]       = sintab[tid];
    ss[tid + 128] = sintab[tid + 128];
    __syncthreads();
    if (tid >= N1) return;
    const int k2 = tid;
    v2f acc = (v2f){0.f, 0.f};
#pragma unroll 4
    for (int j2 = 0; j2 < G; ++j2) {
        const v2f u = sU[j2];
        int ph = (k2 * j2) & 255;
        const v2f t = (v2f){ss[(ph + 64) & 255], ss[ph]};
        CFMA_CONJ(acc, u, t);
    }
    float res = ((k1 + k2) & 1) ? -acc.x : acc.x;
    out[((size_t)b * N1 + k1) * N1 + k2] = res;
}

// ---------------------------------------------------------------------------
extern "C" void kernel_launch(void* const* d_in, const int* in_sizes, int n_in,
                              void* d_out, int out_size, void* d_ws, size_t ws_size,
                              hipStream_t stream) {
    const float* r   = (const float*)d_in[0];
    const float* w1r = (const float*)d_in[1];
    const float* w1i = (const float*)d_in[2];
    const float* w2r = (const float*)d_in[3];
    const float* w2i = (const float*)d_in[4];
    const float* w3r = (const float*)d_in[5];
    const float* w3i = (const float*)d_in[6];
    const float* wtr = (const float*)d_in[7];
    const float* wti = (const float*)d_in[8];
    float* out = (float*)d_out;

    float* ws = (float*)d_ws;
    const size_t g = (size_t)GG;

    // ---- fixed region ---------------------------------------------------
    const size_t SZ16 = (size_t)NB*CH*CH*9;
    const size_t SZ1  = (size_t)NB*CH*9;
    const size_t SZ5  = (size_t)NB*16*25;
    const size_t SZ7  = (size_t)NB*16*49;
    float* p = ws;
    float* SIN  = p; p += 1024;
    float* A3R = p; p += SZ16;  float* A3I = p; p += SZ16;
    float* A2R = p; p += SZ16;  float* A2I = p; p += SZ16;
    float* A1R = p; p += SZ1;   float* A1I = p; p += SZ1;
    float* C5R = p; p += SZ5;   float* C5I = p; p += SZ5;
    float* C7FR = p; p += SZ7;  float* C7FI = p; p += SZ7;
    float* Q5R = p; p += SZ5;   float* Q5I = p; p += SZ5;
    float* C7AR = p; p += SZ7;  float* C7AI = p; p += SZ7;
    const size_t extraFloats = (size_t)(p - ws);

    // ---- chunking: per-sample floats ------------------------------------
    const size_t sampFloats = g + 2*g + 2*g + 2*g + (5*g)/2 + g/2;  // 10g
    size_t availFloats = ws_size / 4;
    long long usable = (long long)availFloats - (long long)extraFloats;
    int cbm = 1;
    if (usable > 0) {
        long long c = usable / (long long)sampFloats;
        cbm = (int)(c < 1 ? 1 : (c > NB ? NB : c));
    }

    float* base = ws + extraFloats;
    float* RHAT = base;                            // [cb][GG]
    float* S1r  = RHAT + (size_t)cbm*g;
    float* S1i  = S1r + (size_t)cbm*g;
    float* S2r  = S1i + (size_t)cbm*g;
    float* S2i  = S2r + (size_t)cbm*g;
    float* HCc  = S2i + (size_t)cbm*g;             // [cb][GG][2]
    float* PTA  = HCc + (size_t)cbm*2*g;           // [cb][16][4][5][256][2] = 2.5g
    float* CAc  = PTA + (size_t)cbm*((5*g)/2);     // [cb][16][4][2][256][2] = 0.5g
    float* T1D  = S2r;                             // overlay (dead before strip_mid)
    float* Uc   = S1r;                             // overlay (dead before fft1)

    // ---- one-time prep --------------------------------------------------
    hipLaunchKernelGGL(init_sintab, dim3(1), dim3(256), 0, stream, SIN);
    hipLaunchKernelGGL(prep_adj16, dim3((unsigned)((SZ16+255)/256)), dim3(256), 0, stream,
                       w3r, w3i, A3R, A3I);
    hipLaunchKernelGGL(prep_adj16, dim3((unsigned)((SZ16+255)/256)), dim3(256), 0, stream,
                       w2r, w2i, A2R, A2I);
    hipLaunchKernelGGL(prep_adj1,  dim3((unsigned)((SZ1+255)/256)),  dim3(256), 0, stream,
                       w1r, w1i, A1R, A1I);
    hipLaunchKernelGGL((compose_k<16,16,1,3,3>), dim3((unsigned)((NB*16*25+255)/256)), dim3(256),
                       0, stream, w2r, w2i, w1r, w1i, C5R, C5I);
    hipLaunchKernelGGL((compose_k<16,16,1,3,5>), dim3((unsigned)((NB*16*49+255)/256)), dim3(256),
                       0, stream, w3r, w3i, C5R, C5I, C7FR, C7FI);
    hipLaunchKernelGGL((compose_k<1,16,16,3,3>), dim3((unsigned)((NB*16*25+255)/256)), dim3(256),
                       0, stream, A1R, A1I, A2R, A2I, Q5R, Q5I);
    hipLaunchKernelGGL((compose_k<1,16,16,5,3>), dim3((unsigned)((NB*16*49+255)/256)), dim3(256),
                       0, stream, Q5R, Q5I, A3R, A3I, C7AR, C7AI);

    // ---- per-chunk pipeline --------------------------------------------
    for (int b0 = 0; b0 < NB; b0 += cbm) {
        const int cb = (NB - b0) < cbm ? (NB - b0) : cbm;

        const float* r_c    = r    + (size_t)b0 * N1 * N1;
        const float* w1r_c  = w1r  + (size_t)b0 * 144;
        const float* w1i_c  = w1i  + (size_t)b0 * 144;
        const float* w2r_c  = w2r  + (size_t)b0 * 2304;
        const float* w2i_c  = w2i  + (size_t)b0 * 2304;
        const float* w3r_c  = w3r  + (size_t)b0 * 2304;
        const float* w3i_c  = w3i  + (size_t)b0 * 2304;
        const float* a3r_c  = A3R  + (size_t)b0 * 2304;
        const float* a3i_c  = A3I  + (size_t)b0 * 2304;
        const float* a2r_c  = A2R  + (size_t)b0 * 2304;
        const float* a2i_c  = A2I  + (size_t)b0 * 2304;
        const float* a1r_c  = A1R  + (size_t)b0 * 144;
        const float* a1i_c  = A1I  + (size_t)b0 * 144;
        const float* c7fr_c = C7FR + (size_t)b0 * 784;
        const float* c7fi_c = C7FI + (size_t)b0 * 784;
        const float* c7ar_c = C7AR + (size_t)b0 * 784;
        const float* c7ai_c = C7AI + (size_t)b0 * 784;
        const float* wtr_c  = wtr  + (size_t)b0 * CH * GG;
        const float* wti_c  = wti  + (size_t)b0 * CH * GG;
        float* out_c = out + (size_t)b0 * N1 * N1;

        hipLaunchKernelGGL(dst_stage1, dim3((cb*G*N1 + 255)/256), dim3(256), 0, stream,
                           r_c, SIN, T1D, cb);
        hipLaunchKernelGGL(dst_stage2, dim3(cb*256), dim3(256), 0, stream,
                           T1D, SIN, RHAT);

        // forward strip chain -> corrected A band (CAc)
        hipLaunchKernelGGL(strip_fwd1, dim3(4, cb), dim3(256), 0, stream,
                           RHAT, w1r_c, w1i_c, S1r, S1i);
        hipLaunchKernelGGL(strip_mid, dim3(16, cb), dim3(256), 0, stream,
                           S1r, S1i, w2r_c, w2i_c, S2r, S2i);
        hipLaunchKernelGGL(strip_fin_ca, dim3(16, cb), dim3(256), 0, stream,
                           S2r, S2i, w3r_c, w3i_c, CAc);

        // fused fwd + theta + adjoint conv
        hipLaunchKernelGGL(fused7_kernel, dim3(64*cb), dim3(256), 0, stream,
                           RHAT, wtr_c, wti_c, c7fr_c, c7fi_c, c7ar_c, c7ai_c,
                           CAc, HCc, PTA, cb);

        // adjoint strip chain -> HC border correction
        hipLaunchKernelGGL(strip_adj1_packed, dim3(16, cb), dim3(256), 0, stream,
                           PTA, a3r_c, a3i_c, S1r, S1i);
        hipLaunchKernelGGL(strip_mid, dim3(16, cb), dim3(256), 0, stream,
                           S1r, S1i, a2r_c, a2i_c, S2r, S2i);
        hipLaunchKernelGGL(strip_fin1, dim3(16, cb), dim3(256), 0, stream,
                           S2r, S2i, a1r_c, a1i_c, HCc);

        hipLaunchKernelGGL(fft_stage1, dim3(16*cb), dim3(256), 0, stream,
                           HCc, SIN, Uc);
        hipLaunchKernelGGL(fft_stage2, dim3(cb*N1), dim3(128), 0, stream,
                           Uc, SIN, out_c);
    }
}

// Round 19
// 888.846 us; speedup vs baseline: 1.0971x; 1.0971x over previous
//
#include <hip/hip_runtime.h>
#include <hip/hip_bf16.h>
#include <math.h>

#define NB 32
#define CH 16
#define N1 127
#define G 256
#define GG (G*G)

typedef float v2f __attribute__((ext_vector_type(2)));

// acc(lo=Re,hi=Im) += complex(x) * complex(w);  x=(xr,xi), w=(wr,wi)
#define CFMA(acc, x, w) do { \
  asm("v_pk_fma_f32 %0, %1, %2, %0 op_sel:[0,0,0] op_sel_hi:[0,1,1]" \
      : "+v"(acc) : "v"(x), "v"(w)); \
  asm("v_pk_fma_f32 %0, %1, %2, %0 op_sel:[1,1,0] op_sel_hi:[1,0,1] neg_lo:[0,1,0]" \
      : "+v"(acc) : "v"(x), "v"(w)); \
} while (0)
// acc += complex(x) * conj(t);  t=(c,s):  re += xr c + xi s;  im += xi c - xr s
#define CFMA_CONJ(acc, x, t) do { \
  asm("v_pk_fma_f32 %0, %1, %2, %0 op_sel:[0,0,0] op_sel_hi:[1,0,1]" \
      : "+v"(acc) : "v"(x), "v"(t)); \
  asm("v_pk_fma_f32 %0, %1, %2, %0 op_sel:[1,1,0] op_sel_hi:[0,1,1] neg_hi:[0,1,0]" \
      : "+v"(acc) : "v"(x), "v"(t)); \
} while (0)
// acc += real(x.lo) * complex(w)
#define RFMA_LO(acc, x, w) \
  asm("v_pk_fma_f32 %0, %1, %2, %0 op_sel:[0,0,0] op_sel_hi:[0,1,1]" \
      : "+v"(acc) : "v"(x), "v"(w))
// acc += real(x.hi) * complex(w)
#define RFMA_HI(acc, x, w) \
  asm("v_pk_fma_f32 %0, %1, %2, %0 op_sel:[1,0,0] op_sel_hi:[1,1,1]" \
      : "+v"(acc) : "v"(x), "v"(w))

// ---------------------------------------------------------------------------
__global__ void init_sintab(float* __restrict__ sintab) {
    int t = threadIdx.x;
    sintab[t] = sinf(6.28318530717958647692f * (float)t / 256.0f);
}

// adj(w)[b,a,c,ky,kx] = conj(w[b,c,a,kx,ky])
__global__ __launch_bounds__(256) void prep_adj16(
    const float* __restrict__ wr, const float* __restrict__ wi,
    float* __restrict__ our, float* __restrict__ oui) {
    int idx = blockIdx.x * 256 + threadIdx.x;
    if (idx >= NB*CH*CH*9) return;
    int tap = idx % 9; int t = idx / 9;
    int c = t % CH; t /= CH;
    int a = t % CH; int b = t / CH;
    int ky = tap / 3, kx = tap % 3;
    int src = ((b*CH + c)*CH + a)*9 + kx*3 + ky;
    our[idx] = wr[src];
    oui[idx] = -wi[src];
}

__global__ __launch_bounds__(256) void prep_adj1(
    const float* __restrict__ wr, const float* __restrict__ wi,
    float* __restrict__ our, float* __restrict__ oui) {
    int idx = blockIdx.x * 256 + threadIdx.x;
    if (idx >= NB*CH*9) return;
    int tap = idx % 9; int t = idx / 9;
    int c = t % CH; int b = t / CH;
    int ky = tap / 3, kx = tap % 3;
    int src = (b*CH + c)*9 + kx*3 + ky;
    our[idx] = wr[src];
    oui[idx] = -wi[src];
}

// ---------------------------------------------------------------------------
// Kernel-tap composition: R[t] = sum_{a+b=t} P[a] Q[b]  (complex), contract CM
template<int CO, int CM, int CI, int KP, int KQ>
__global__ __launch_bounds__(256) void compose_k(
    const float* __restrict__ Pr, const float* __restrict__ Pi,
    const float* __restrict__ Qr, const float* __restrict__ Qi,
    float* __restrict__ Rr, float* __restrict__ Ri) {
    constexpr int T = KP + KQ - 1;
    int idx = blockIdx.x * 256 + threadIdx.x;
    if (idx >= NB*CO*CI*T*T) return;
    int txp = idx % T; int t = idx / T;
    int typ = t % T; t /= T;
    int ci = t % CI; t /= CI;
    int co = t % CO; int b = t / CO;
    float ar = 0.f, ai = 0.f;
    for (int m = 0; m < CM; ++m) {
        const float* pr = Pr + (((size_t)b*CO + co)*CM + m)*KP*KP;
        const float* pi = Pi + (((size_t)b*CO + co)*CM + m)*KP*KP;
        const float* qr = Qr + (((size_t)b*CM + m)*CI + ci)*KQ*KQ;
        const float* qi = Qi + (((size_t)b*CM + m)*CI + ci)*KQ*KQ;
        for (int ay = 0; ay < KP; ++ay) {
            int by = typ - ay; if (by < 0 || by >= KQ) continue;
            for (int ax = 0; ax < KP; ++ax) {
                int bx = txp - ax; if (bx < 0 || bx >= KQ) continue;
                float prr = pr[ay*KP+ax], pii = pi[ay*KP+ax];
                float qrr = qr[by*KQ+bx], qii = qi[by*KQ+bx];
                ar += prr*qrr - pii*qii;
                ai += prr*qii + pii*qrr;
            }
        }
    }
    Rr[idx] = ar; Ri[idx] = ai;
}

// ---------------------------------------------------------------------------
// DST stage 1  ((-1)^K folded into sin index)
__global__ __launch_bounds__(256) void dst_stage1(
    const float* __restrict__ r, const float* __restrict__ sintab,
    float* __restrict__ T1, int nb) {
    __shared__ float ss[256];
    ss[threadIdx.x] = sintab[threadIdx.x];
    __syncthreads();
    int idx = blockIdx.x * 256 + threadIdx.x;
    if (idx >= nb*G*N1) return;
    int kk = idx % N1;
    int t = idx / N1;
    int j1 = t & 255; int b = t >> 8;
    const float* rb = r + b * N1 * N1;
    const int j1s = (j1 + 128) & 255;
    float acc = 0.f;
    for (int K = 1; K <= N1; ++K) {
        acc = fmaf(ss[(j1s * K) & 255], rb[(K - 1) * N1 + kk], acc);
    }
    T1[idx] = acc;
}

// DST stage 2
__global__ __launch_bounds__(256) void dst_stage2(
    const float* __restrict__ T1, const float* __restrict__ sintab,
    float* __restrict__ rhat) {
    __shared__ float ss[256];
    ss[threadIdx.x] = sintab[threadIdx.x];
    __syncthreads();
    int idx = blockIdx.x * 256 + threadIdx.x;
    int j2 = idx & 255;
    int t = idx >> 8;
    int j1 = t & 255; int b = t >> 8;
    const float* t1 = T1 + ((size_t)b * G + j1) * N1;
    const int j2s = (j2 + 128) & 255;
    float acc = 0.f;
    for (int kk = 0; kk < N1; ++kk) {
        acc = fmaf(ss[(j2s * (kk + 1)) & 255], t1[kk], acc);
    }
    rhat[idx] = acc * (-4.0f / 65536.0f);
}

// ---------------------------------------------------------------------------
// FUSED conv kernel (champion config): per 32x32 HC tile, compute composed fwd
// A on the fly from a 44x44 rhat halo (stride 44, 176B rows), patch border
// from CAc, theta-multiply into single sTA buffer, accumulate composed adjoint
// 7x7. LDS weight tables; theta loaded just-in-time (covered by A-compute).
__global__ __launch_bounds__(256) void fused7_kernel(
    const float* __restrict__ rhat,
    const float* __restrict__ tr, const float* __restrict__ ti,   // [b][16][GG]
    const float* __restrict__ w7fr, const float* __restrict__ w7fi, // [b][16][49]
    const float* __restrict__ w7ar, const float* __restrict__ w7ai, // [b][16][49]
    const float* __restrict__ CAc,  // [b][16][4][2][256][2] corrected A band
    float* __restrict__ HCc, float* __restrict__ PTA, int cb) {
    __shared__ float sR[44*44];        // rhat halo, stride 44
    __shared__ float sTA[38*38*2];     // theta*A staged (single buffer)
    __shared__ float sWf[16*49*2];
    __shared__ float sWa[16*49*2];
    const int lin = blockIdx.x;        // 64*cb blocks
    const int swz = (lin & 7) * (8 * cb) + (lin >> 3);
    const int b = swz >> 6;
    const int tile = swz & 63;
    const int x0 = (tile & 7) * 32;
    const int y0 = (tile >> 3) * 32;
    const int tid = threadIdx.x;
    const bool border = (x0 == 0) | (x0 == 224) | (y0 == 0) | (y0 == 224);
    {
        const float* fr = w7fr + (size_t)b*784; const float* fi = w7fi + (size_t)b*784;
        const float* ar = w7ar + (size_t)b*784; const float* ai = w7ai + (size_t)b*784;
        for (int t = tid; t < 784; t += 256) {
            sWf[2*t] = fr[t]; sWf[2*t+1] = fi[t];
            sWa[2*t] = ar[t]; sWa[2*t+1] = ai[t];
        }
    }
    {
        const float* rb = rhat + (size_t)b * GG;
        for (int t = tid; t < 44*44; t += 256) {
            int ry = t / 44, rx = t - ry*44;
            int gy = y0 - 6 + ry, gx = x0 - 6 + rx;
            bool ok = ((unsigned)gy < G) & ((unsigned)gx < G);
            sR[ry*44 + rx] = ok ? rb[gy*G + gx] : 0.f;
        }
    }
    // A-phase mapping: 190 active threads, each owns 8 consecutive A-halo px
    const bool act = tid < 190;
    const int arow = act ? (tid % 38) : 0;   // A-halo row 0..37
    const int cg   = act ? (tid / 38) : 0;   // col group (8 px)
    // adj mapping: thread owns 4 consecutive outputs in one row
    const int ty = tid >> 3, txi = tid & 7;
    v2f hacc[4];
#pragma unroll
    for (int k = 0; k < 4; ++k) hacc[k] = (v2f){0.f, 0.f};
    const size_t planeT = (size_t)b * 16 * GG;
    __syncthreads();

    for (int ci = 0; ci < 16; ++ci) {
        // ---- theta loads for this ci (issued early, hidden by A compute) --
        float thr[8], thi[8];
        const int pgy = y0 - 3 + arow;
        if (act) {
            const float* trc = tr + planeT + (size_t)ci * GG;
            const float* tic = ti + planeT + (size_t)ci * GG;
#pragma unroll
            for (int k = 0; k < 8; ++k) {
                int acol = 8*cg + k;
                int pgx = x0 - 3 + acol;
                bool ok = (acol < 38) & ((unsigned)pgy < G) & ((unsigned)pgx < G);
                thr[k] = ok ? trc[pgy*G + pgx] : 0.f;
                thi[k] = ok ? tic[pgy*G + pgx] : 0.f;
            }
        }
        // ---- A-halo compute (composed fwd 7x7, real input, pk fma) -------
        v2f aa[8];
#pragma unroll
        for (int k = 0; k < 8; ++k) aa[k] = (v2f){0.f, 0.f};
        if (act) {
            const float* wci = &sWf[ci*49*2];
#pragma unroll
            for (int dy = 0; dy < 7; ++dy) {
                const float* rp = &sR[(arow + dy)*44 + 8*cg];
                v2f fv[8];
#pragma unroll
                for (int q = 0; q < 4; ++q) {
                    const float4 vv = *reinterpret_cast<const float4*>(&rp[4*q]);
                    fv[2*q]   = (v2f){vv.x, vv.y};
                    fv[2*q+1] = (v2f){vv.z, vv.w};
                }
#pragma unroll
                for (int dx = 0; dx < 7; ++dx) {
                    const v2f wv = *reinterpret_cast<const v2f*>(&wci[(dy*7+dx)*2]);
                    const int h = dx >> 1;
                    if ((dx & 1) == 0) {
#pragma unroll
                        for (int m = 0; m < 4; ++m) {
                            RFMA_LO(aa[2*m],   fv[h+m], wv);
                            RFMA_HI(aa[2*m+1], fv[h+m], wv);
                        }
                    } else {
#pragma unroll
                        for (int m = 0; m < 4; ++m) {
                            RFMA_HI(aa[2*m],   fv[h+m],   wv);
                            RFMA_LO(aa[2*m+1], fv[h+m+1], wv);
                        }
                    }
                }
            }
            // patch 2-px border band with corrected A from strip chain
            if (border) {
#pragma unroll
                for (int k = 0; k < 8; ++k) {
                    int acol = 8*cg + k;
                    int gx = x0 - 3 + acol;
                    if (acol < 38 && (unsigned)pgy < G && (unsigned)gx < G) {
                        int s = -1, uu = 0, vv = 0;
                        if (pgy < 2)        { s = 0; uu = pgy;       vv = gx;  }
                        else if (pgy >= 254){ s = 1; uu = pgy - 254; vv = gx;  }
                        else if (gx < 2)    { s = 2; uu = gx;        vv = pgy; }
                        else if (gx >= 254) { s = 3; uu = gx - 254;  vv = pgy; }
                        if (s >= 0) {
                            size_t o = ((((size_t)b*16 + ci)*4 + s)*2 + uu)*256 + vv;
                            aa[k] = *reinterpret_cast<const v2f*>(&CAc[o*2]);
                        }
                    }
                }
            }
        }
        __syncthreads();   // all waves done reading sTA for ci-1
        // ---- theta*A -> sTA (+ PTA extraction on border tiles) -----------
        if (act) {
#pragma unroll
            for (int k = 0; k < 8; ++k) {
                int acol = 8*cg + k;
                if (acol < 38) {
                    float hr = fmaf(aa[k].x, thr[k], -aa[k].y*thi[k]);
                    float hi = fmaf(aa[k].x, thi[k],  aa[k].y*thr[k]);
                    *reinterpret_cast<v2f*>(&sTA[(arow*38 + acol)*2]) = (v2f){hr, hi};
                    if (border) {
                        int gx = x0 - 3 + acol;
                        if ((unsigned)pgy < G && (unsigned)gx < G) {
                            const size_t cbase = ((size_t)b*16 + ci) * 4;
                            if (pgy < 5)    { size_t o = ((cbase+0)*5 + pgy      )*256 + gx;  *reinterpret_cast<v2f*>(&PTA[2*o]) = (v2f){hr,hi}; }
                            if (pgy >= 251) { size_t o = ((cbase+1)*5 + pgy - 251)*256 + gx;  *reinterpret_cast<v2f*>(&PTA[2*o]) = (v2f){hr,hi}; }
                            if (gx < 5)     { size_t o = ((cbase+2)*5 + gx       )*256 + pgy; *reinterpret_cast<v2f*>(&PTA[2*o]) = (v2f){hr,hi}; }
                            if (gx >= 251)  { size_t o = ((cbase+3)*5 + gx - 251 )*256 + pgy; *reinterpret_cast<v2f*>(&PTA[2*o]) = (v2f){hr,hi}; }
                        }
                    }
                }
            }
        }
        __syncthreads();   // sTA ready
        // ---- adjoint accumulate ------------------------------------------
        {
            const float* wci = &sWa[ci*49*2];
#pragma unroll
            for (int dy = 0; dy < 7; ++dy) {
                const float* rowp = &sTA[((ty + dy)*38 + txi*4)*2];
                v2f win[10];
#pragma unroll
                for (int q = 0; q < 5; ++q) {
                    const float4 vv = *reinterpret_cast<const float4*>(&rowp[q*4]);
                    win[2*q]   = (v2f){vv.x, vv.y};
                    win[2*q+1] = (v2f){vv.z, vv.w};
                }
#pragma unroll
                for (int dx = 0; dx < 7; ++dx) {
                    const v2f wv = *reinterpret_cast<const v2f*>(&wci[(dy*7+dx)*2]);
#pragma unroll
                    for (int k = 0; k < 4; ++k)
                        CFMA(hacc[k], win[k+dx], wv);
                }
            }
        }
    }

    const size_t outB = (size_t)b * GG;
    const int oy = y0 + ty, ox = x0 + txi*4;
    float4 o0 = make_float4(hacc[0].x, hacc[0].y, hacc[1].x, hacc[1].y);
    float4 o1 = make_float4(hacc[2].x, hacc[2].y, hacc[3].x, hacc[3].y);
    *reinterpret_cast<float4*>(&HCc[(outB + oy*G + ox)*2])     = o0;
    *reinterpret_cast<float4*>(&HCc[(outB + oy*G + ox)*2 + 4]) = o1;
}

// ---------------------------------------------------------------------------
// Strip machinery. strip s: 0=TOP, 1=BOT, 2=LEF, 3=RIG. [b][ch][s][u:4][v:256].
__device__ __forceinline__ size_t sidx(int b, int ch, int s, int u, int v) {
    return ((((size_t)b*CH + ch)*4 + s)*4 + u)*256 + v;
}
__device__ __forceinline__ void spos(int s, int u, int v, int& y, int& x) {
    y = (s == 0) ? u : (s == 1) ? 252 + u : v;
    x = (s == 2) ? u : (s == 3) ? 252 + u : v;
}

// stage 1 fwd: conv1 (w1, 1->16, real rhat) exact, all u in [0,4)
__global__ __launch_bounds__(256) void strip_fwd1(
    const float* __restrict__ rhat,
    const float* __restrict__ w1r_, const float* __restrict__ w1i_, // [b][16][9]
    float* __restrict__ S1r, float* __restrict__ S1i) {
    __shared__ float sW[16*9*2];
    const int s = blockIdx.x, b = blockIdx.y;
    for (int t = threadIdx.x; t < 144; t += 256) {
        sW[2*t] = w1r_[(size_t)b*144 + t]; sW[2*t+1] = w1i_[(size_t)b*144 + t];
    }
    __syncthreads();
    const int v = threadIdx.x;
    const float* rb = rhat + (size_t)b * GG;
    for (int u = 0; u < 4; ++u) {
        int y, x; spos(s, u, v, y, x);
        float xv[9];
#pragma unroll
        for (int dy = -1; dy <= 1; ++dy)
#pragma unroll
            for (int dx = -1; dx <= 1; ++dx) {
                int gy = y + dy, gx = x + dx;
                bool ok = ((unsigned)gy < G) & ((unsigned)gx < G);
                xv[(dy+1)*3 + dx+1] = ok ? rb[gy*G+gx] : 0.f;
            }
#pragma unroll
        for (int co = 0; co < 16; ++co) {
            float ar = 0.f, ai = 0.f;
#pragma unroll
            for (int tap = 0; tap < 9; ++tap) {
                ar = fmaf(xv[tap], sW[(co*9+tap)*2], ar);
                ai = fmaf(xv[tap], sW[(co*9+tap)*2+1], ai);
            }
            S1r[sidx(b, co, s, u, v)] = ar;
            S1i[sidx(b, co, s, u, v)] = ai;
        }
    }
}

// stage 1 adj (packed): a3-conv on packed theta.*A bands. u in [0,4). pk_fma.
__global__ __launch_bounds__(256) void strip_adj1_packed(
    const float* __restrict__ PTA,   // [b][ci][4][5][256][2]
    const float* __restrict__ wr_, const float* __restrict__ wi_, // [b][16][16][9]
    float* __restrict__ S1r, float* __restrict__ S1i) {
    __shared__ float sW[16*16*9*2];
    const int s = blockIdx.x >> 2, vt = blockIdx.x & 3, b = blockIdx.y;
    for (int t = threadIdx.x; t < 2304; t += 256) {
        sW[2*t] = wr_[(size_t)b*2304 + t]; sW[2*t+1] = wi_[(size_t)b*2304 + t];
    }
    __syncthreads();
    const int v = vt * 64 + (threadIdx.x & 63);
    const int u = threadIdx.x >> 6;           // 0..3
    const int off = (s == 1 || s == 3) ? 1 : 0;
    v2f acc[16];
#pragma unroll
    for (int co = 0; co < 16; ++co) acc[co] = (v2f){0.f, 0.f};
    for (int ci = 0; ci < 16; ++ci) {
        const float* base = PTA + ((((size_t)b*16 + ci)*4 + s)*5) * 512;
        v2f n2[9];
#pragma unroll
        for (int dy = -1; dy <= 1; ++dy)
#pragma unroll
            for (int dx = -1; dx <= 1; ++dx) {
                int pu = (s < 2) ? (u + off + dy) : (u + off + dx);
                int vp = (s < 2) ? (v + dx) : (v + dy);
                v2f val = (v2f){0.f, 0.f};
                if (((unsigned)pu < 5u) & ((unsigned)vp < 256u))
                    val = *reinterpret_cast<const v2f*>(&base[(pu*256 + vp)*2]);
                n2[(dy+1)*3+dx+1] = val;
            }
#pragma unroll
        for (int co = 0; co < 16; ++co)
#pragma unroll
            for (int tap = 0; tap < 9; ++tap) {
                const v2f wv = *reinterpret_cast<const v2f*>(&sW[((co*16+ci)*9+tap)*2]);
                CFMA(acc[co], n2[tap], wv);
            }
    }
#pragma unroll
    for (int co = 0; co < 16; ++co) {
        S1r[sidx(b, co, s, u, v)] = acc[co].x;
        S1i[sidx(b, co, s, u, v)] = acc[co].y;
    }
}

// stage 2: 16->16 conv strips->strips, u in [u0, u0+3). grid (16, cb). pk_fma.
__global__ __launch_bounds__(256) void strip_mid(
    const float* __restrict__ Ar, const float* __restrict__ Ai,
    const float* __restrict__ wr_, const float* __restrict__ wi_, // [b][16][16][9]
    float* __restrict__ Br, float* __restrict__ Bi) {
    __shared__ float sW[16*16*9*2];
    const int s = blockIdx.x >> 2, vt = blockIdx.x & 3, b = blockIdx.y;
    for (int t = threadIdx.x; t < 2304; t += 256) {
        sW[2*t] = wr_[(size_t)b*2304 + t]; sW[2*t+1] = wi_[(size_t)b*2304 + t];
    }
    __syncthreads();
    const int v = vt * 64 + (threadIdx.x & 63);
    const int uslot = threadIdx.x >> 6;
    if (uslot >= 3) return;
    const int u0 = (s == 1 || s == 3) ? 1 : 0;
    const int u = u0 + uslot;
    int y, x; spos(s, u, v, y, x);
    v2f acc[16];
#pragma unroll
    for (int co = 0; co < 16; ++co) acc[co] = (v2f){0.f, 0.f};
    for (int ci = 0; ci < 16; ++ci) {
        v2f n2[9];
#pragma unroll
        for (int dy = -1; dy <= 1; ++dy)
#pragma unroll
            for (int dx = -1; dx <= 1; ++dx) {
                int gy = y + dy, gx = x + dx;
                v2f val = (v2f){0.f, 0.f};
                if (((unsigned)gy < G) & ((unsigned)gx < G)) {
                    int up = (s < 2) ? u + dy : u + dx;
                    int vp = (s < 2) ? v + dx : v + dy;
                    size_t ix = sidx(b, ci, s, up, vp);
                    val.x = Ar[ix]; val.y = Ai[ix];
                }
                n2[(dy+1)*3+dx+1] = val;
            }
#pragma unroll
        for (int co = 0; co < 16; ++co)
#pragma unroll
            for (int tap = 0; tap < 9; ++tap) {
                const v2f wv = *reinterpret_cast<const v2f*>(&sW[((co*16+ci)*9+tap)*2]);
                CFMA(acc[co], n2[tap], wv);
            }
    }
#pragma unroll
    for (int co = 0; co < 16; ++co) {
        Br[sidx(b, co, s, u, v)] = acc[co].x;
        Bi[sidx(b, co, s, u, v)] = acc[co].y;
    }
}

// stage 3 fwd variant: 16 ch from strips -> compact corrected-A band CAc.
__global__ __launch_bounds__(256) void strip_fin_ca(
    const float* __restrict__ Ar, const float* __restrict__ Ai,
    const float* __restrict__ wr_, const float* __restrict__ wi_, // [b][16][16][9]
    float* __restrict__ CAc) {
    __shared__ float sW[16*16*9*2];
    const int s = blockIdx.x >> 2, vt = blockIdx.x & 3, b = blockIdx.y;
    for (int t = threadIdx.x; t < 2304; t += 256) {
        sW[2*t] = wr_[(size_t)b*2304 + t]; sW[2*t+1] = wi_[(size_t)b*2304 + t];
    }
    __syncthreads();
    const int v = vt * 64 + (threadIdx.x & 63);
    const int uslot = threadIdx.x >> 6;
    if (uslot >= 2) return;
    const int u0 = (s == 1 || s == 3) ? 2 : 0;
    const int u = u0 + uslot;
    int y, x; spos(s, u, v, y, x);
    v2f acc[16];
#pragma unroll
    for (int co = 0; co < 16; ++co) acc[co] = (v2f){0.f, 0.f};
    for (int ci = 0; ci < 16; ++ci) {
        v2f n2[9];
#pragma unroll
        for (int dy = -1; dy <= 1; ++dy)
#pragma unroll
            for (int dx = -1; dx <= 1; ++dx) {
                int gy = y + dy, gx = x + dx;
                v2f val = (v2f){0.f, 0.f};
                if (((unsigned)gy < G) & ((unsigned)gx < G)) {
                    int up = (s < 2) ? u + dy : u + dx;
                    int vp = (s < 2) ? v + dx : v + dy;
                    size_t ix = sidx(b, ci, s, up, vp);
                    val.x = Ar[ix]; val.y = Ai[ix];
                }
                n2[(dy+1)*3+dx+1] = val;
            }
#pragma unroll
        for (int co = 0; co < 16; ++co)
#pragma unroll
            for (int tap = 0; tap < 9; ++tap) {
                const v2f wv = *reinterpret_cast<const v2f*>(&sW[((co*16+ci)*9+tap)*2]);
                CFMA(acc[co], n2[tap], wv);
            }
    }
#pragma unroll
    for (int co = 0; co < 16; ++co) {
        size_t o = ((((size_t)b*16 + co)*4 + s)*2 + uslot)*256 + v;
        *reinterpret_cast<v2f*>(&CAc[o*2]) = acc[co];
    }
}

// stage 3 adj: 1 ch from strips -> overwrite band in interleaved HCc.
__global__ __launch_bounds__(256) void strip_fin1(
    const float* __restrict__ Ar, const float* __restrict__ Ai,
    const float* __restrict__ wr_, const float* __restrict__ wi_, // [b][1][16][9]
    float* __restrict__ Oc) {
    __shared__ float sW[16*9*2];
    const int s = blockIdx.x >> 2, vt = blockIdx.x & 3, b = blockIdx.y;
    for (int t = threadIdx.x; t < 144; t += 256) {
        sW[2*t] = wr_[(size_t)b*144 + t]; sW[2*t+1] = wi_[(size_t)b*144 + t];
    }
    __syncthreads();
    const int v = vt * 64 + (threadIdx.x & 63);
    const int uslot = threadIdx.x >> 6;
    if (uslot >= 2) return;
    const int u0 = (s == 1 || s == 3) ? 2 : 0;
    const int u = u0 + uslot;
    int y, x; spos(s, u, v, y, x);
    v2f acc = (v2f){0.f, 0.f};
    for (int ci = 0; ci < 16; ++ci) {
#pragma unroll
        for (int dy = -1; dy <= 1; ++dy)
#pragma unroll
            for (int dx = -1; dx <= 1; ++dx) {
                int gy = y + dy, gx = x + dx;
                v2f val = (v2f){0.f, 0.f};
                if (((unsigned)gy < G) & ((unsigned)gx < G)) {
                    int up = (s < 2) ? u + dy : u + dx;
                    int vp = (s < 2) ? v + dx : v + dy;
                    size_t ix = sidx(b, ci, s, up, vp);
                    val.x = Ar[ix]; val.y = Ai[ix];
                }
                const v2f wv = *reinterpret_cast<const v2f*>(&sW[(ci*9 + (dy+1)*3 + dx+1)*2]);
                CFMA(acc, val, wv);
            }
    }
    *reinterpret_cast<v2f*>(&Oc[(((size_t)b)*GG + y*G + x)*2]) = acc;
}

// ---------------------------------------------------------------------------
// FFT stage 1 (tiled GEMM): U[b][k1][j2] = sum_j1 HC[b][j1][j2] e^{-2pi i k1 j1/256}.
__global__ __launch_bounds__(256) void fft_stage1(
    const float* __restrict__ HCc, const float* __restrict__ sintab,
    float* __restrict__ Uc) {
    __shared__ v2f sHC[64][16];
    __shared__ v2f sTW[256];
    const int jt = blockIdx.x & 15;
    const int b  = blockIdx.x >> 4;
    const int tid = threadIdx.x;
    {
        int ph = tid;
        sTW[tid] = (v2f){sintab[(ph + 64) & 255], sintab[ph]};  // (c, s)
    }
    const int j2c = tid & 15;
    const int kg  = tid >> 4;           // 0..15
    const int j2  = jt * 16 + j2c;
    const float* hc = HCc + ((size_t)b * GG + j2) * 2;
    v2f acc[8];
    int ph[8];
#pragma unroll
    for (int i = 0; i < 8; ++i) { acc[i] = (v2f){0.f, 0.f}; ph[i] = 0; }
    for (int c = 0; c < 4; ++c) {
        __syncthreads();
#pragma unroll
        for (int q = 0; q < 4; ++q) {
            int jj = 16*q + kg;
            sHC[jj][j2c] = *reinterpret_cast<const v2f*>(&hc[((size_t)(c*64 + jj) * G) * 2]);
        }
        __syncthreads();
#pragma unroll 8
        for (int jj = 0; jj < 64; ++jj) {
            const v2f x = sHC[jj][j2c];
#pragma unroll
            for (int i = 0; i < 8; ++i) {
                const v2f t = sTW[ph[i]];
                CFMA_CONJ(acc[i], x, t);
                ph[i] = (ph[i] + kg + 16*i) & 255;
            }
        }
    }
#pragma unroll
    for (int i = 0; i < 8; ++i) {
        int k1 = kg + 16*i;
        if (k1 < N1)
            *reinterpret_cast<v2f*>(&Uc[(((size_t)b * N1 + k1) * G + j2) * 2]) = acc[i];
    }
}

// FFT stage 2: e[b][k1][k2] = (-1)^{k1+k2} Re( sum_j2 U[..] e^{-2pi i k2 j2/256} ).
__global__ __launch_bounds__(128) void fft_stage2(
    const float* __restrict__ Uc, const float* __restrict__ sintab,
    float* __restrict__ out) {
    __shared__ v2f sU[256];
    __shared__ float ss[256];
    const int k1 = blockIdx.x % N1;
    const int b  = blockIdx.x / N1;
    const int tid = threadIdx.x;
    const float* uc = Uc + ((size_t)b * N1 + k1) * G * 2;
    sU[tid]       = *reinterpret_cast<const v2f*>(&uc[tid * 2]);
    sU[tid + 128] = *reinterpret_cast<const v2f*>(&uc[(tid + 128) * 2]);
    ss[tid]       = sintab[tid];
    ss[tid + 128] = sintab[tid + 128];
    __syncthreads();
    if (tid >= N1) return;
    const int k2 = tid;
    v2f acc = (v2f){0.f, 0.f};
#pragma unroll 4
    for (int j2 = 0; j2 < G; ++j2) {
        const v2f u = sU[j2];
        int ph = (k2 * j2) & 255;
        const v2f t = (v2f){ss[(ph + 64) & 255], ss[ph]};
        CFMA_CONJ(acc, u, t);
    }
    float res = ((k1 + k2) & 1) ? -acc.x : acc.x;
    out[((size_t)b * N1 + k1) * N1 + k2] = res;
}

// ---------------------------------------------------------------------------
extern "C" void kernel_launch(void* const* d_in, const int* in_sizes, int n_in,
                              void* d_out, int out_size, void* d_ws, size_t ws_size,
                              hipStream_t stream) {
    const float* r   = (const float*)d_in[0];
    const float* w1r = (const float*)d_in[1];
    const float* w1i = (const float*)d_in[2];
    const float* w2r = (const float*)d_in[3];
    const float* w2i = (const float*)d_in[4];
    const float* w3r = (const float*)d_in[5];
    const float* w3i = (const float*)d_in[6];
    const float* wtr = (const float*)d_in[7];
    const float* wti = (const float*)d_in[8];
    float* out = (float*)d_out;

    float* ws = (float*)d_ws;
    const size_t g = (size_t)GG;

    // ---- fixed region ---------------------------------------------------
    const size_t SZ16 = (size_t)NB*CH*CH*9;
    const size_t SZ1  = (size_t)NB*CH*9;
    const size_t SZ5  = (size_t)NB*16*25;
    const size_t SZ7  = (size_t)NB*16*49;
    float* p = ws;
    float* SIN  = p; p += 1024;
    float* A3R = p; p += SZ16;  float* A3I = p; p += SZ16;
    float* A2R = p; p += SZ16;  float* A2I = p; p += SZ16;
    float* A1R = p; p += SZ1;   float* A1I = p; p += SZ1;
    float* C5R = p; p += SZ5;   float* C5I = p; p += SZ5;
    float* C7FR = p; p += SZ7;  float* C7FI = p; p += SZ7;
    float* Q5R = p; p += SZ5;   float* Q5I = p; p += SZ5;
    float* C7AR = p; p += SZ7;  float* C7AI = p; p += SZ7;
    const size_t extraFloats = (size_t)(p - ws);

    // ---- chunking: per-sample floats ------------------------------------
    const size_t sampFloats = g + 2*g + 2*g + 2*g + (5*g)/2 + g/2;  // 10g
    size_t availFloats = ws_size / 4;
    long long usable = (long long)availFloats - (long long)extraFloats;
    int cbm = 1;
    if (usable > 0) {
        long long c = usable / (long long)sampFloats;
        cbm = (int)(c < 1 ? 1 : (c > NB ? NB : c));
    }

    float* base = ws + extraFloats;
    float* RHAT = base;                            // [cb][GG]
    float* S1r  = RHAT + (size_t)cbm*g;
    float* S1i  = S1r + (size_t)cbm*g;
    float* S2r  = S1i + (size_t)cbm*g;
    float* S2i  = S2r + (size_t)cbm*g;
    float* HCc  = S2i + (size_t)cbm*g;             // [cb][GG][2]
    float* PTA  = HCc + (size_t)cbm*2*g;           // [cb][16][4][5][256][2] = 2.5g
    float* CAc  = PTA + (size_t)cbm*((5*g)/2);     // [cb][16][4][2][256][2] = 0.5g
    float* T1D  = S2r;                             // overlay (dead before strip_mid)
    float* Uc   = S1r;                             // overlay (dead before fft1)

    // ---- one-time prep --------------------------------------------------
    hipLaunchKernelGGL(init_sintab, dim3(1), dim3(256), 0, stream, SIN);
    hipLaunchKernelGGL(prep_adj16, dim3((unsigned)((SZ16+255)/256)), dim3(256), 0, stream,
                       w3r, w3i, A3R, A3I);
    hipLaunchKernelGGL(prep_adj16, dim3((unsigned)((SZ16+255)/256)), dim3(256), 0, stream,
                       w2r, w2i, A2R, A2I);
    hipLaunchKernelGGL(prep_adj1,  dim3((unsigned)((SZ1+255)/256)),  dim3(256), 0, stream,
                       w1r, w1i, A1R, A1I);
    hipLaunchKernelGGL((compose_k<16,16,1,3,3>), dim3((unsigned)((NB*16*25+255)/256)), dim3(256),
                       0, stream, w2r, w2i, w1r, w1i, C5R, C5I);
    hipLaunchKernelGGL((compose_k<16,16,1,3,5>), dim3((unsigned)((NB*16*49+255)/256)), dim3(256),
                       0, stream, w3r, w3i, C5R, C5I, C7FR, C7FI);
    hipLaunchKernelGGL((compose_k<1,16,16,3,3>), dim3((unsigned)((NB*16*25+255)/256)), dim3(256),
                       0, stream, A1R, A1I, A2R, A2I, Q5R, Q5I);
    hipLaunchKernelGGL((compose_k<1,16,16,5,3>), dim3((unsigned)((NB*16*49+255)/256)), dim3(256),
                       0, stream, Q5R, Q5I, A3R, A3I, C7AR, C7AI);

    // ---- per-chunk pipeline --------------------------------------------
    for (int b0 = 0; b0 < NB; b0 += cbm) {
        const int cb = (NB - b0) < cbm ? (NB - b0) : cbm;

        const float* r_c    = r    + (size_t)b0 * N1 * N1;
        const float* w1r_c  = w1r  + (size_t)b0 * 144;
        const float* w1i_c  = w1i  + (size_t)b0 * 144;
        const float* w2r_c  = w2r  + (size_t)b0 * 2304;
        const float* w2i_c  = w2i  + (size_t)b0 * 2304;
        const float* w3r_c  = w3r  + (size_t)b0 * 2304;
        const float* w3i_c  = w3i  + (size_t)b0 * 2304;
        const float* a3r_c  = A3R  + (size_t)b0 * 2304;
        const float* a3i_c  = A3I  + (size_t)b0 * 2304;
        const float* a2r_c  = A2R  + (size_t)b0 * 2304;
        const float* a2i_c  = A2I  + (size_t)b0 * 2304;
        const float* a1r_c  = A1R  + (size_t)b0 * 144;
        const float* a1i_c  = A1I  + (size_t)b0 * 144;
        const float* c7fr_c = C7FR + (size_t)b0 * 784;
        const float* c7fi_c = C7FI + (size_t)b0 * 784;
        const float* c7ar_c = C7AR + (size_t)b0 * 784;
        const float* c7ai_c = C7AI + (size_t)b0 * 784;
        const float* wtr_c  = wtr  + (size_t)b0 * CH * GG;
        const float* wti_c  = wti  + (size_t)b0 * CH * GG;
        float* out_c = out + (size_t)b0 * N1 * N1;

        hipLaunchKernelGGL(dst_stage1, dim3((cb*G*N1 + 255)/256), dim3(256), 0, stream,
                           r_c, SIN, T1D, cb);
        hipLaunchKernelGGL(dst_stage2, dim3(cb*256), dim3(256), 0, stream,
                           T1D, SIN, RHAT);

        // forward strip chain -> corrected A band (CAc)
        hipLaunchKernelGGL(strip_fwd1, dim3(4, cb), dim3(256), 0, stream,
                           RHAT, w1r_c, w1i_c, S1r, S1i);
        hipLaunchKernelGGL(strip_mid, dim3(16, cb), dim3(256), 0, stream,
                           S1r, S1i, w2r_c, w2i_c, S2r, S2i);
        hipLaunchKernelGGL(strip_fin_ca, dim3(16, cb), dim3(256), 0, stream,
                           S2r, S2i, w3r_c, w3i_c, CAc);

        // fused fwd + theta + adjoint conv
        hipLaunchKernelGGL(fused7_kernel, dim3(64*cb), dim3(256), 0, stream,
                           RHAT, wtr_c, wti_c, c7fr_c, c7fi_c, c7ar_c, c7ai_c,
                           CAc, HCc, PTA, cb);

        // adjoint strip chain -> HC border correction
        hipLaunchKernelGGL(strip_adj1_packed, dim3(16, cb), dim3(256), 0, stream,
                           PTA, a3r_c, a3i_c, S1r, S1i);
        hipLaunchKernelGGL(strip_mid, dim3(16, cb), dim3(256), 0, stream,
                           S1r, S1i, a2r_c, a2i_c, S2r, S2i);
        hipLaunchKernelGGL(strip_fin1, dim3(16, cb), dim3(256), 0, stream,
                           S2r, S2i, a1r_c, a1i_c, HCc);

        hipLaunchKernelGGL(fft_stage1, dim3(16*cb), dim3(256), 0, stream,
                           HCc, SIN, Uc);
        hipLaunchKernelGGL(fft_stage2, dim3(cb*N1), dim3(128), 0, stream,
                           Uc, SIN, out_c);
    }
}

// Round 20
// 863.879 us; speedup vs baseline: 1.1288x; 1.0289x over previous
//
#include <hip/hip_runtime.h>
#include <hip/hip_bf16.h>
#include <math.h>

#define NB 32
#define CH 16
#define N1 127
#define G 256
#define GG (G*G)

typedef float v2f __attribute__((ext_vector_type(2)));

// acc(lo=Re,hi=Im) += complex(x) * complex(w);  x=(xr,xi), w=(wr,wi)
#define CFMA(acc, x, w) do { \
  asm("v_pk_fma_f32 %0, %1, %2, %0 op_sel:[0,0,0] op_sel_hi:[0,1,1]" \
      : "+v"(acc) : "v"(x), "v"(w)); \
  asm("v_pk_fma_f32 %0, %1, %2, %0 op_sel:[1,1,0] op_sel_hi:[1,0,1] neg_lo:[0,1,0]" \
      : "+v"(acc) : "v"(x), "v"(w)); \
} while (0)
// acc += complex(x) * conj(t);  t=(c,s):  re += xr c + xi s;  im += xi c - xr s
#define CFMA_CONJ(acc, x, t) do { \
  asm("v_pk_fma_f32 %0, %1, %2, %0 op_sel:[0,0,0] op_sel_hi:[1,0,1]" \
      : "+v"(acc) : "v"(x), "v"(t)); \
  asm("v_pk_fma_f32 %0, %1, %2, %0 op_sel:[1,1,0] op_sel_hi:[0,1,1] neg_hi:[0,1,0]" \
      : "+v"(acc) : "v"(x), "v"(t)); \
} while (0)
// acc += real(x.lo) * complex(w)
#define RFMA_LO(acc, x, w) \
  asm("v_pk_fma_f32 %0, %1, %2, %0 op_sel:[0,0,0] op_sel_hi:[0,1,1]" \
      : "+v"(acc) : "v"(x), "v"(w))
// acc += real(x.hi) * complex(w)
#define RFMA_HI(acc, x, w) \
  asm("v_pk_fma_f32 %0, %1, %2, %0 op_sel:[1,0,0] op_sel_hi:[1,1,1]" \
      : "+v"(acc) : "v"(x), "v"(w))

// ---------------------------------------------------------------------------
__global__ void init_sintab(float* __restrict__ sintab) {
    int t = threadIdx.x;
    sintab[t] = sinf(6.28318530717958647692f * (float)t / 256.0f);
}

// adj(w)[b,a,c,ky,kx] = conj(w[b,c,a,kx,ky])
__global__ __launch_bounds__(256) void prep_adj16(
    const float* __restrict__ wr, const float* __restrict__ wi,
    float* __restrict__ our, float* __restrict__ oui) {
    int idx = blockIdx.x * 256 + threadIdx.x;
    if (idx >= NB*CH*CH*9) return;
    int tap = idx % 9; int t = idx / 9;
    int c = t % CH; t /= CH;
    int a = t % CH; int b = t / CH;
    int ky = tap / 3, kx = tap % 3;
    int src = ((b*CH + c)*CH + a)*9 + kx*3 + ky;
    our[idx] = wr[src];
    oui[idx] = -wi[src];
}

__global__ __launch_bounds__(256) void prep_adj1(
    const float* __restrict__ wr, const float* __restrict__ wi,
    float* __restrict__ our, float* __restrict__ oui) {
    int idx = blockIdx.x * 256 + threadIdx.x;
    if (idx >= NB*CH*9) return;
    int tap = idx % 9; int t = idx / 9;
    int c = t % CH; int b = t / CH;
    int ky = tap / 3, kx = tap % 3;
    int src = (b*CH + c)*9 + kx*3 + ky;
    our[idx] = wr[src];
    oui[idx] = -wi[src];
}

// ---------------------------------------------------------------------------
// Kernel-tap composition: R[t] = sum_{a+b=t} P[a] Q[b]  (complex), contract CM
template<int CO, int CM, int CI, int KP, int KQ>
__global__ __launch_bounds__(256) void compose_k(
    const float* __restrict__ Pr, const float* __restrict__ Pi,
    const float* __restrict__ Qr, const float* __restrict__ Qi,
    float* __restrict__ Rr, float* __restrict__ Ri) {
    constexpr int T = KP + KQ - 1;
    int idx = blockIdx.x * 256 + threadIdx.x;
    if (idx >= NB*CO*CI*T*T) return;
    int txp = idx % T; int t = idx / T;
    int typ = t % T; t /= T;
    int ci = t % CI; t /= CI;
    int co = t % CO; int b = t / CO;
    float ar = 0.f, ai = 0.f;
    for (int m = 0; m < CM; ++m) {
        const float* pr = Pr + (((size_t)b*CO + co)*CM + m)*KP*KP;
        const float* pi = Pi + (((size_t)b*CO + co)*CM + m)*KP*KP;
        const float* qr = Qr + (((size_t)b*CM + m)*CI + ci)*KQ*KQ;
        const float* qi = Qi + (((size_t)b*CM + m)*CI + ci)*KQ*KQ;
        for (int ay = 0; ay < KP; ++ay) {
            int by = typ - ay; if (by < 0 || by >= KQ) continue;
            for (int ax = 0; ax < KP; ++ax) {
                int bx = txp - ax; if (bx < 0 || bx >= KQ) continue;
                float prr = pr[ay*KP+ax], pii = pi[ay*KP+ax];
                float qrr = qr[by*KQ+bx], qii = qi[by*KQ+bx];
                ar += prr*qrr - pii*qii;
                ai += prr*qii + pii*qrr;
            }
        }
    }
    Rr[idx] = ar; Ri[idx] = ai;
}

// ---------------------------------------------------------------------------
// DST stage 1  ((-1)^K folded into sin index)
__global__ __launch_bounds__(256) void dst_stage1(
    const float* __restrict__ r, const float* __restrict__ sintab,
    float* __restrict__ T1, int nb) {
    __shared__ float ss[256];
    ss[threadIdx.x] = sintab[threadIdx.x];
    __syncthreads();
    int idx = blockIdx.x * 256 + threadIdx.x;
    if (idx >= nb*G*N1) return;
    int kk = idx % N1;
    int t = idx / N1;
    int j1 = t & 255; int b = t >> 8;
    const float* rb = r + b * N1 * N1;
    const int j1s = (j1 + 128) & 255;
    float acc = 0.f;
    for (int K = 1; K <= N1; ++K) {
        acc = fmaf(ss[(j1s * K) & 255], rb[(K - 1) * N1 + kk], acc);
    }
    T1[idx] = acc;
}

// DST stage 2
__global__ __launch_bounds__(256) void dst_stage2(
    const float* __restrict__ T1, const float* __restrict__ sintab,
    float* __restrict__ rhat) {
    __shared__ float ss[256];
    ss[threadIdx.x] = sintab[threadIdx.x];
    __syncthreads();
    int idx = blockIdx.x * 256 + threadIdx.x;
    int j2 = idx & 255;
    int t = idx >> 8;
    int j1 = t & 255; int b = t >> 8;
    const float* t1 = T1 + ((size_t)b * G + j1) * N1;
    const int j2s = (j2 + 128) & 255;
    float acc = 0.f;
    for (int kk = 0; kk < N1; ++kk) {
        acc = fmaf(ss[(j2s * (kk + 1)) & 255], t1[kk], acc);
    }
    rhat[idx] = acc * (-4.0f / 65536.0f);
}

// ---------------------------------------------------------------------------
// FUSED conv kernel (champion config): per 32x32 HC tile, compute composed fwd
// A on the fly from a 44x44 rhat halo (stride 44, 176B rows), patch border
// from CAc, theta-multiply into single sTA buffer, accumulate composed adjoint
// 7x7. LDS weight tables; theta loaded just-in-time (covered by A-compute).
__global__ __launch_bounds__(256) void fused7_kernel(
    const float* __restrict__ rhat,
    const float* __restrict__ tr, const float* __restrict__ ti,   // [b][16][GG]
    const float* __restrict__ w7fr, const float* __restrict__ w7fi, // [b][16][49]
    const float* __restrict__ w7ar, const float* __restrict__ w7ai, // [b][16][49]
    const float* __restrict__ CAc,  // [b][16][4][2][256][2] corrected A band
    float* __restrict__ HCc, float* __restrict__ PTA, int cb) {
    __shared__ float sR[44*44];        // rhat halo, stride 44
    __shared__ float sTA[38*38*2];     // theta*A staged (single buffer)
    __shared__ float sWf[16*49*2];
    __shared__ float sWa[16*49*2];
    const int lin = blockIdx.x;        // 64*cb blocks
    const int swz = (lin & 7) * (8 * cb) + (lin >> 3);
    const int b = swz >> 6;
    const int tile = swz & 63;
    const int x0 = (tile & 7) * 32;
    const int y0 = (tile >> 3) * 32;
    const int tid = threadIdx.x;
    const bool border = (x0 == 0) | (x0 == 224) | (y0 == 0) | (y0 == 224);
    {
        const float* fr = w7fr + (size_t)b*784; const float* fi = w7fi + (size_t)b*784;
        const float* ar = w7ar + (size_t)b*784; const float* ai = w7ai + (size_t)b*784;
        for (int t = tid; t < 784; t += 256) {
            sWf[2*t] = fr[t]; sWf[2*t+1] = fi[t];
            sWa[2*t] = ar[t]; sWa[2*t+1] = ai[t];
        }
    }
    {
        const float* rb = rhat + (size_t)b * GG;
        for (int t = tid; t < 44*44; t += 256) {
            int ry = t / 44, rx = t - ry*44;
            int gy = y0 - 6 + ry, gx = x0 - 6 + rx;
            bool ok = ((unsigned)gy < G) & ((unsigned)gx < G);
            sR[ry*44 + rx] = ok ? rb[gy*G + gx] : 0.f;
        }
    }
    // A-phase mapping: 190 active threads, each owns 8 consecutive A-halo px
    const bool act = tid < 190;
    const int arow = act ? (tid % 38) : 0;   // A-halo row 0..37
    const int cg   = act ? (tid / 38) : 0;   // col group (8 px)
    // adj mapping: thread owns 4 consecutive outputs in one row
    const int ty = tid >> 3, txi = tid & 7;
    v2f hacc[4];
#pragma unroll
    for (int k = 0; k < 4; ++k) hacc[k] = (v2f){0.f, 0.f};
    const size_t planeT = (size_t)b * 16 * GG;
    __syncthreads();

    for (int ci = 0; ci < 16; ++ci) {
        // ---- theta loads for this ci (issued early, hidden by A compute) --
        float thr[8], thi[8];
        const int pgy = y0 - 3 + arow;
        if (act) {
            const float* trc = tr + planeT + (size_t)ci * GG;
            const float* tic = ti + planeT + (size_t)ci * GG;
#pragma unroll
            for (int k = 0; k < 8; ++k) {
                int acol = 8*cg + k;
                int pgx = x0 - 3 + acol;
                bool ok = (acol < 38) & ((unsigned)pgy < G) & ((unsigned)pgx < G);
                thr[k] = ok ? trc[pgy*G + pgx] : 0.f;
                thi[k] = ok ? tic[pgy*G + pgx] : 0.f;
            }
        }
        // ---- A-halo compute (composed fwd 7x7, real input, pk fma) -------
        v2f aa[8];
#pragma unroll
        for (int k = 0; k < 8; ++k) aa[k] = (v2f){0.f, 0.f};
        if (act) {
            const float* wci = &sWf[ci*49*2];
#pragma unroll
            for (int dy = 0; dy < 7; ++dy) {
                const float* rp = &sR[(arow + dy)*44 + 8*cg];
                v2f fv[8];
#pragma unroll
                for (int q = 0; q < 4; ++q) {
                    const float4 vv = *reinterpret_cast<const float4*>(&rp[4*q]);
                    fv[2*q]   = (v2f){vv.x, vv.y};
                    fv[2*q+1] = (v2f){vv.z, vv.w};
                }
#pragma unroll
                for (int dx = 0; dx < 7; ++dx) {
                    const v2f wv = *reinterpret_cast<const v2f*>(&wci[(dy*7+dx)*2]);
                    const int h = dx >> 1;
                    if ((dx & 1) == 0) {
#pragma unroll
                        for (int m = 0; m < 4; ++m) {
                            RFMA_LO(aa[2*m],   fv[h+m], wv);
                            RFMA_HI(aa[2*m+1], fv[h+m], wv);
                        }
                    } else {
#pragma unroll
                        for (int m = 0; m < 4; ++m) {
                            RFMA_HI(aa[2*m],   fv[h+m],   wv);
                            RFMA_LO(aa[2*m+1], fv[h+m+1], wv);
                        }
                    }
                }
            }
            // patch 2-px border band with corrected A from strip chain
            if (border) {
#pragma unroll
                for (int k = 0; k < 8; ++k) {
                    int acol = 8*cg + k;
                    int gx = x0 - 3 + acol;
                    if (acol < 38 && (unsigned)pgy < G && (unsigned)gx < G) {
                        int s = -1, uu = 0, vv = 0;
                        if (pgy < 2)        { s = 0; uu = pgy;       vv = gx;  }
                        else if (pgy >= 254){ s = 1; uu = pgy - 254; vv = gx;  }
                        else if (gx < 2)    { s = 2; uu = gx;        vv = pgy; }
                        else if (gx >= 254) { s = 3; uu = gx - 254;  vv = pgy; }
                        if (s >= 0) {
                            size_t o = ((((size_t)b*16 + ci)*4 + s)*2 + uu)*256 + vv;
                            aa[k] = *reinterpret_cast<const v2f*>(&CAc[o*2]);
                        }
                    }
                }
            }
        }
        __syncthreads();   // all waves done reading sTA for ci-1
        // ---- theta*A -> sTA (+ PTA extraction on border tiles) -----------
        if (act) {
#pragma unroll
            for (int k = 0; k < 8; ++k) {
                int acol = 8*cg + k;
                if (acol < 38) {
                    float hr = fmaf(aa[k].x, thr[k], -aa[k].y*thi[k]);
                    float hi = fmaf(aa[k].x, thi[k],  aa[k].y*thr[k]);
                    *reinterpret_cast<v2f*>(&sTA[(arow*38 + acol)*2]) = (v2f){hr, hi};
                    if (border) {
                        int gx = x0 - 3 + acol;
                        if ((unsigned)pgy < G && (unsigned)gx < G) {
                            const size_t cbase = ((size_t)b*16 + ci) * 4;
                            if (pgy < 5)    { size_t o = ((cbase+0)*5 + pgy      )*256 + gx;  *reinterpret_cast<v2f*>(&PTA[2*o]) = (v2f){hr,hi}; }
                            if (pgy >= 251) { size_t o = ((cbase+1)*5 + pgy - 251)*256 + gx;  *reinterpret_cast<v2f*>(&PTA[2*o]) = (v2f){hr,hi}; }
                            if (gx < 5)     { size_t o = ((cbase+2)*5 + gx       )*256 + pgy; *reinterpret_cast<v2f*>(&PTA[2*o]) = (v2f){hr,hi}; }
                            if (gx >= 251)  { size_t o = ((cbase+3)*5 + gx - 251 )*256 + pgy; *reinterpret_cast<v2f*>(&PTA[2*o]) = (v2f){hr,hi}; }
                        }
                    }
                }
            }
        }
        __syncthreads();   // sTA ready
        // ---- adjoint accumulate ------------------------------------------
        {
            const float* wci = &sWa[ci*49*2];
#pragma unroll
            for (int dy = 0; dy < 7; ++dy) {
                const float* rowp = &sTA[((ty + dy)*38 + txi*4)*2];
                v2f win[10];
#pragma unroll
                for (int q = 0; q < 5; ++q) {
                    const float4 vv = *reinterpret_cast<const float4*>(&rowp[q*4]);
                    win[2*q]   = (v2f){vv.x, vv.y};
                    win[2*q+1] = (v2f){vv.z, vv.w};
                }
#pragma unroll
                for (int dx = 0; dx < 7; ++dx) {
                    const v2f wv = *reinterpret_cast<const v2f*>(&wci[(dy*7+dx)*2]);
#pragma unroll
                    for (int k = 0; k < 4; ++k)
                        CFMA(hacc[k], win[k+dx], wv);
                }
            }
        }
    }

    const size_t outB = (size_t)b * GG;
    const int oy = y0 + ty, ox = x0 + txi*4;
    float4 o0 = make_float4(hacc[0].x, hacc[0].y, hacc[1].x, hacc[1].y);
    float4 o1 = make_float4(hacc[2].x, hacc[2].y, hacc[3].x, hacc[3].y);
    *reinterpret_cast<float4*>(&HCc[(outB + oy*G + ox)*2])     = o0;
    *reinterpret_cast<float4*>(&HCc[(outB + oy*G + ox)*2 + 4]) = o1;
}

// ---------------------------------------------------------------------------
// Strip machinery. strip s: 0=TOP, 1=BOT, 2=LEF, 3=RIG. [b][ch][s][u:4][v:256].
__device__ __forceinline__ size_t sidx(int b, int ch, int s, int u, int v) {
    return ((((size_t)b*CH + ch)*4 + s)*4 + u)*256 + v;
}
__device__ __forceinline__ void spos(int s, int u, int v, int& y, int& x) {
    y = (s == 0) ? u : (s == 1) ? 252 + u : v;
    x = (s == 2) ? u : (s == 3) ? 252 + u : v;
}

// stage 1 fwd: conv1 (w1, 1->16, real rhat) exact, all u in [0,4)
__global__ __launch_bounds__(256) void strip_fwd1(
    const float* __restrict__ rhat,
    const float* __restrict__ w1r_, const float* __restrict__ w1i_, // [b][16][9]
    float* __restrict__ S1r, float* __restrict__ S1i) {
    __shared__ float sW[16*9*2];
    const int s = blockIdx.x, b = blockIdx.y;
    for (int t = threadIdx.x; t < 144; t += 256) {
        sW[2*t] = w1r_[(size_t)b*144 + t]; sW[2*t+1] = w1i_[(size_t)b*144 + t];
    }
    __syncthreads();
    const int v = threadIdx.x;
    const float* rb = rhat + (size_t)b * GG;
    for (int u = 0; u < 4; ++u) {
        int y, x; spos(s, u, v, y, x);
        float xv[9];
#pragma unroll
        for (int dy = -1; dy <= 1; ++dy)
#pragma unroll
            for (int dx = -1; dx <= 1; ++dx) {
                int gy = y + dy, gx = x + dx;
                bool ok = ((unsigned)gy < G) & ((unsigned)gx < G);
                xv[(dy+1)*3 + dx+1] = ok ? rb[gy*G+gx] : 0.f;
            }
#pragma unroll
        for (int co = 0; co < 16; ++co) {
            float ar = 0.f, ai = 0.f;
#pragma unroll
            for (int tap = 0; tap < 9; ++tap) {
                ar = fmaf(xv[tap], sW[(co*9+tap)*2], ar);
                ai = fmaf(xv[tap], sW[(co*9+tap)*2+1], ai);
            }
            S1r[sidx(b, co, s, u, v)] = ar;
            S1i[sidx(b, co, s, u, v)] = ai;
        }
    }
}

// stage 1 adj (packed): a3-conv on packed theta.*A bands. u in [0,4). pk_fma.
__global__ __launch_bounds__(256) void strip_adj1_packed(
    const float* __restrict__ PTA,   // [b][ci][4][5][256][2]
    const float* __restrict__ wr_, const float* __restrict__ wi_, // [b][16][16][9]
    float* __restrict__ S1r, float* __restrict__ S1i) {
    __shared__ float sW[16*16*9*2];
    const int s = blockIdx.x >> 2, vt = blockIdx.x & 3, b = blockIdx.y;
    for (int t = threadIdx.x; t < 2304; t += 256) {
        sW[2*t] = wr_[(size_t)b*2304 + t]; sW[2*t+1] = wi_[(size_t)b*2304 + t];
    }
    __syncthreads();
    const int v = vt * 64 + (threadIdx.x & 63);
    const int u = threadIdx.x >> 6;           // 0..3
    const int off = (s == 1 || s == 3) ? 1 : 0;
    v2f acc[16];
#pragma unroll
    for (int co = 0; co < 16; ++co) acc[co] = (v2f){0.f, 0.f};
    for (int ci = 0; ci < 16; ++ci) {
        const float* base = PTA + ((((size_t)b*16 + ci)*4 + s)*5) * 512;
        v2f n2[9];
#pragma unroll
        for (int dy = -1; dy <= 1; ++dy)
#pragma unroll
            for (int dx = -1; dx <= 1; ++dx) {
                int pu = (s < 2) ? (u + off + dy) : (u + off + dx);
                int vp = (s < 2) ? (v + dx) : (v + dy);
                v2f val = (v2f){0.f, 0.f};
                if (((unsigned)pu < 5u) & ((unsigned)vp < 256u))
                    val = *reinterpret_cast<const v2f*>(&base[(pu*256 + vp)*2]);
                n2[(dy+1)*3+dx+1] = val;
            }
#pragma unroll
        for (int co = 0; co < 16; ++co)
#pragma unroll
            for (int tap = 0; tap < 9; ++tap) {
                const v2f wv = *reinterpret_cast<const v2f*>(&sW[((co*16+ci)*9+tap)*2]);
                CFMA(acc[co], n2[tap], wv);
            }
    }
#pragma unroll
    for (int co = 0; co < 16; ++co) {
        S1r[sidx(b, co, s, u, v)] = acc[co].x;
        S1i[sidx(b, co, s, u, v)] = acc[co].y;
    }
}

// stage 2: 16->16 conv strips->strips, u in [u0, u0+3). grid (16, cb). pk_fma.
__global__ __launch_bounds__(256) void strip_mid(
    const float* __restrict__ Ar, const float* __restrict__ Ai,
    const float* __restrict__ wr_, const float* __restrict__ wi_, // [b][16][16][9]
    float* __restrict__ Br, float* __restrict__ Bi) {
    __shared__ float sW[16*16*9*2];
    const int s = blockIdx.x >> 2, vt = blockIdx.x & 3, b = blockIdx.y;
    for (int t = threadIdx.x; t < 2304; t += 256) {
        sW[2*t] = wr_[(size_t)b*2304 + t]; sW[2*t+1] = wi_[(size_t)b*2304 + t];
    }
    __syncthreads();
    const int v = vt * 64 + (threadIdx.x & 63);
    const int uslot = threadIdx.x >> 6;
    if (uslot >= 3) return;
    const int u0 = (s == 1 || s == 3) ? 1 : 0;
    const int u = u0 + uslot;
    int y, x; spos(s, u, v, y, x);
    v2f acc[16];
#pragma unroll
    for (int co = 0; co < 16; ++co) acc[co] = (v2f){0.f, 0.f};
    for (int ci = 0; ci < 16; ++ci) {
        v2f n2[9];
#pragma unroll
        for (int dy = -1; dy <= 1; ++dy)
#pragma unroll
            for (int dx = -1; dx <= 1; ++dx) {
                int gy = y + dy, gx = x + dx;
                v2f val = (v2f){0.f, 0.f};
                if (((unsigned)gy < G) & ((unsigned)gx < G)) {
                    int up = (s < 2) ? u + dy : u + dx;
                    int vp = (s < 2) ? v + dx : v + dy;
                    size_t ix = sidx(b, ci, s, up, vp);
                    val.x = Ar[ix]; val.y = Ai[ix];
                }
                n2[(dy+1)*3+dx+1] = val;
            }
#pragma unroll
        for (int co = 0; co < 16; ++co)
#pragma unroll
            for (int tap = 0; tap < 9; ++tap) {
                const v2f wv = *reinterpret_cast<const v2f*>(&sW[((co*16+ci)*9+tap)*2]);
                CFMA(acc[co], n2[tap], wv);
            }
    }
#pragma unroll
    for (int co = 0; co < 16; ++co) {
        Br[sidx(b, co, s, u, v)] = acc[co].x;
        Bi[sidx(b, co, s, u, v)] = acc[co].y;
    }
}

// stage 3 fwd variant: 16 ch from strips -> compact corrected-A band CAc.
__global__ __launch_bounds__(256) void strip_fin_ca(
    const float* __restrict__ Ar, const float* __restrict__ Ai,
    const float* __restrict__ wr_, const float* __restrict__ wi_, // [b][16][16][9]
    float* __restrict__ CAc) {
    __shared__ float sW[16*16*9*2];
    const int s = blockIdx.x >> 2, vt = blockIdx.x & 3, b = blockIdx.y;
    for (int t = threadIdx.x; t < 2304; t += 256) {
        sW[2*t] = wr_[(size_t)b*2304 + t]; sW[2*t+1] = wi_[(size_t)b*2304 + t];
    }
    __syncthreads();
    const int v = vt * 64 + (threadIdx.x & 63);
    const int uslot = threadIdx.x >> 6;
    if (uslot >= 2) return;
    const int u0 = (s == 1 || s == 3) ? 2 : 0;
    const int u = u0 + uslot;
    int y, x; spos(s, u, v, y, x);
    v2f acc[16];
#pragma unroll
    for (int co = 0; co < 16; ++co) acc[co] = (v2f){0.f, 0.f};
    for (int ci = 0; ci < 16; ++ci) {
        v2f n2[9];
#pragma unroll
        for (int dy = -1; dy <= 1; ++dy)
#pragma unroll
            for (int dx = -1; dx <= 1; ++dx) {
                int gy = y + dy, gx = x + dx;
                v2f val = (v2f){0.f, 0.f};
                if (((unsigned)gy < G) & ((unsigned)gx < G)) {
                    int up = (s < 2) ? u + dy : u + dx;
                    int vp = (s < 2) ? v + dx : v + dy;
                    size_t ix = sidx(b, ci, s, up, vp);
                    val.x = Ar[ix]; val.y = Ai[ix];
                }
                n2[(dy+1)*3+dx+1] = val;
            }
#pragma unroll
        for (int co = 0; co < 16; ++co)
#pragma unroll
            for (int tap = 0; tap < 9; ++tap) {
                const v2f wv = *reinterpret_cast<const v2f*>(&sW[((co*16+ci)*9+tap)*2]);
                CFMA(acc[co], n2[tap], wv);
            }
    }
#pragma unroll
    for (int co = 0; co < 16; ++co) {
        size_t o = ((((size_t)b*16 + co)*4 + s)*2 + uslot)*256 + v;
        *reinterpret_cast<v2f*>(&CAc[o*2]) = acc[co];
    }
}

// stage 3 adj: 1 ch from strips -> overwrite band in interleaved HCc.
__global__ __launch_bounds__(256) void strip_fin1(
    const float* __restrict__ Ar, const float* __restrict__ Ai,
    const float* __restrict__ wr_, const float* __restrict__ wi_, // [b][1][16][9]
    float* __restrict__ Oc) {
    __shared__ float sW[16*9*2];
    const int s = blockIdx.x >> 2, vt = blockIdx.x & 3, b = blockIdx.y;
    for (int t = threadIdx.x; t < 144; t += 256) {
        sW[2*t] = wr_[(size_t)b*144 + t]; sW[2*t+1] = wi_[(size_t)b*144 + t];
    }
    __syncthreads();
    const int v = vt * 64 + (threadIdx.x & 63);
    const int uslot = threadIdx.x >> 6;
    if (uslot >= 2) return;
    const int u0 = (s == 1 || s == 3) ? 2 : 0;
    const int u = u0 + uslot;
    int y, x; spos(s, u, v, y, x);
    v2f acc = (v2f){0.f, 0.f};
    for (int ci = 0; ci < 16; ++ci) {
#pragma unroll
        for (int dy = -1; dy <= 1; ++dy)
#pragma unroll
            for (int dx = -1; dx <= 1; ++dx) {
                int gy = y + dy, gx = x + dx;
                v2f val = (v2f){0.f, 0.f};
                if (((unsigned)gy < G) & ((unsigned)gx < G)) {
                    int up = (s < 2) ? u + dy : u + dx;
                    int vp = (s < 2) ? v + dx : v + dy;
                    size_t ix = sidx(b, ci, s, up, vp);
                    val.x = Ar[ix]; val.y = Ai[ix];
                }
                const v2f wv = *reinterpret_cast<const v2f*>(&sW[(ci*9 + (dy+1)*3 + dx+1)*2]);
                CFMA(acc, val, wv);
            }
    }
    *reinterpret_cast<v2f*>(&Oc[(((size_t)b)*GG + y*G + x)*2]) = acc;
}

// ---------------------------------------------------------------------------
// FFT stage 1 (tiled GEMM): U[b][k1][j2] = sum_j1 HC[b][j1][j2] e^{-2pi i k1 j1/256}.
__global__ __launch_bounds__(256) void fft_stage1(
    const float* __restrict__ HCc, const float* __restrict__ sintab,
    float* __restrict__ Uc) {
    __shared__ v2f sHC[64][16];
    __shared__ v2f sTW[256];
    const int jt = blockIdx.x & 15;
    const int b  = blockIdx.x >> 4;
    const int tid = threadIdx.x;
    {
        int ph = tid;
        sTW[tid] = (v2f){sintab[(ph + 64) & 255], sintab[ph]};  // (c, s)
    }
    const int j2c = tid & 15;
    const int kg  = tid >> 4;           // 0..15
    const int j2  = jt * 16 + j2c;
    const float* hc = HCc + ((size_t)b * GG + j2) * 2;
    v2f acc[8];
    int ph[8];
#pragma unroll
    for (int i = 0; i < 8; ++i) { acc[i] = (v2f){0.f, 0.f}; ph[i] = 0; }
    for (int c = 0; c < 4; ++c) {
        __syncthreads();
#pragma unroll
        for (int q = 0; q < 4; ++q) {
            int jj = 16*q + kg;
            sHC[jj][j2c] = *reinterpret_cast<const v2f*>(&hc[((size_t)(c*64 + jj) * G) * 2]);
        }
        __syncthreads();
#pragma unroll 8
        for (int jj = 0; jj < 64; ++jj) {
            const v2f x = sHC[jj][j2c];
#pragma unroll
            for (int i = 0; i < 8; ++i) {
                const v2f t = sTW[ph[i]];
                CFMA_CONJ(acc[i], x, t);
                ph[i] = (ph[i] + kg + 16*i) & 255;
            }
        }
    }
#pragma unroll
    for (int i = 0; i < 8; ++i) {
        int k1 = kg + 16*i;
        if (k1 < N1)
            *reinterpret_cast<v2f*>(&Uc[(((size_t)b * N1 + k1) * G + j2) * 2]) = acc[i];
    }
}

// FFT stage 2 (Re-only, v2f twiddle table, incremental phase):
// e[b][k1][k2] = (-1)^{k1+k2} sum_j2 ( Ur c + Ui s ),  (c,s) = tw(k2*j2).
__global__ __launch_bounds__(128) void fft_stage2(
    const float* __restrict__ Uc, const float* __restrict__ sintab,
    float* __restrict__ out) {
    __shared__ v2f sU[256];
    __shared__ v2f sT[256];
    const int k1 = blockIdx.x % N1;
    const int b  = blockIdx.x / N1;
    const int tid = threadIdx.x;
    const float* uc = Uc + ((size_t)b * N1 + k1) * G * 2;
    sU[tid]       = *reinterpret_cast<const v2f*>(&uc[tid * 2]);
    sU[tid + 128] = *reinterpret_cast<const v2f*>(&uc[(tid + 128) * 2]);
    sT[tid]       = (v2f){sintab[(tid + 64) & 255],  sintab[tid]};        // (c,s)
    sT[tid + 128] = (v2f){sintab[(tid + 192) & 255], sintab[tid + 128]};
    __syncthreads();
    if (tid >= N1) return;
    const int k2 = tid;
    float acc = 0.f;
    int ph = 0;
#pragma unroll 4
    for (int j2 = 0; j2 < G; ++j2) {
        const v2f u = sU[j2];
        const v2f t = sT[ph];
        acc = fmaf(u.x, t.x, fmaf(u.y, t.y, acc));
        ph = (ph + k2) & 255;
    }
    float res = ((k1 + k2) & 1) ? -acc : acc;
    out[((size_t)b * N1 + k1) * N1 + k2] = res;
}

// ---------------------------------------------------------------------------
extern "C" void kernel_launch(void* const* d_in, const int* in_sizes, int n_in,
                              void* d_out, int out_size, void* d_ws, size_t ws_size,
                              hipStream_t stream) {
    const float* r   = (const float*)d_in[0];
    const float* w1r = (const float*)d_in[1];
    const float* w1i = (const float*)d_in[2];
    const float* w2r = (const float*)d_in[3];
    const float* w2i = (const float*)d_in[4];
    const float* w3r = (const float*)d_in[5];
    const float* w3i = (const float*)d_in[6];
    const float* wtr = (const float*)d_in[7];
    const float* wti = (const float*)d_in[8];
    float* out = (float*)d_out;

    float* ws = (float*)d_ws;
    const size_t g = (size_t)GG;

    // ---- fixed region ---------------------------------------------------
    const size_t SZ16 = (size_t)NB*CH*CH*9;
    const size_t SZ1  = (size_t)NB*CH*9;
    const size_t SZ5  = (size_t)NB*16*25;
    const size_t SZ7  = (size_t)NB*16*49;
    float* p = ws;
    float* SIN  = p; p += 1024;
    float* A3R = p; p += SZ16;  float* A3I = p; p += SZ16;
    float* A2R = p; p += SZ16;  float* A2I = p; p += SZ16;
    float* A1R = p; p += SZ1;   float* A1I = p; p += SZ1;
    float* C5R = p; p += SZ5;   float* C5I = p; p += SZ5;
    float* C7FR = p; p += SZ7;  float* C7FI = p; p += SZ7;
    float* Q5R = p; p += SZ5;   float* Q5I = p; p += SZ5;
    float* C7AR = p; p += SZ7;  float* C7AI = p; p += SZ7;
    const size_t extraFloats = (size_t)(p - ws);

    // ---- chunking: per-sample floats ------------------------------------
    const size_t sampFloats = g + 2*g + 2*g + 2*g + (5*g)/2 + g/2;  // 10g
    size_t availFloats = ws_size / 4;
    long long usable = (long long)availFloats - (long long)extraFloats;
    int cbm = 1;
    if (usable > 0) {
        long long c = usable / (long long)sampFloats;
        cbm = (int)(c < 1 ? 1 : (c > NB ? NB : c));
    }

    float* base = ws + extraFloats;
    float* RHAT = base;                            // [cb][GG]
    float* S1r  = RHAT + (size_t)cbm*g;
    float* S1i  = S1r + (size_t)cbm*g;
    float* S2r  = S1i + (size_t)cbm*g;
    float* S2i  = S2r + (size_t)cbm*g;
    float* HCc  = S2i + (size_t)cbm*g;             // [cb][GG][2]
    float* PTA  = HCc + (size_t)cbm*2*g;           // [cb][16][4][5][256][2] = 2.5g
    float* CAc  = PTA + (size_t)cbm*((5*g)/2);     // [cb][16][4][2][256][2] = 0.5g
    float* T1D  = S2r;                             // overlay (dead before strip_mid)
    float* Uc   = S1r;                             // overlay (dead before fft1)

    // ---- one-time prep --------------------------------------------------
    hipLaunchKernelGGL(init_sintab, dim3(1), dim3(256), 0, stream, SIN);
    hipLaunchKernelGGL(prep_adj16, dim3((unsigned)((SZ16+255)/256)), dim3(256), 0, stream,
                       w3r, w3i, A3R, A3I);
    hipLaunchKernelGGL(prep_adj16, dim3((unsigned)((SZ16+255)/256)), dim3(256), 0, stream,
                       w2r, w2i, A2R, A2I);
    hipLaunchKernelGGL(prep_adj1,  dim3((unsigned)((SZ1+255)/256)),  dim3(256), 0, stream,
                       w1r, w1i, A1R, A1I);
    hipLaunchKernelGGL((compose_k<16,16,1,3,3>), dim3((unsigned)((NB*16*25+255)/256)), dim3(256),
                       0, stream, w2r, w2i, w1r, w1i, C5R, C5I);
    hipLaunchKernelGGL((compose_k<16,16,1,3,5>), dim3((unsigned)((NB*16*49+255)/256)), dim3(256),
                       0, stream, w3r, w3i, C5R, C5I, C7FR, C7FI);
    hipLaunchKernelGGL((compose_k<1,16,16,3,3>), dim3((unsigned)((NB*16*25+255)/256)), dim3(256),
                       0, stream, A1R, A1I, A2R, A2I, Q5R, Q5I);
    hipLaunchKernelGGL((compose_k<1,16,16,5,3>), dim3((unsigned)((NB*16*49+255)/256)), dim3(256),
                       0, stream, Q5R, Q5I, A3R, A3I, C7AR, C7AI);

    // ---- per-chunk pipeline --------------------------------------------
    for (int b0 = 0; b0 < NB; b0 += cbm) {
        const int cb = (NB - b0) < cbm ? (NB - b0) : cbm;

        const float* r_c    = r    + (size_t)b0 * N1 * N1;
        const float* w1r_c  = w1r  + (size_t)b0 * 144;
        const float* w1i_c  = w1i  + (size_t)b0 * 144;
        const float* w2r_c  = w2r  + (size_t)b0 * 2304;
        const float* w2i_c  = w2i  + (size_t)b0 * 2304;
        const float* w3r_c  = w3r  + (size_t)b0 * 2304;
        const float* w3i_c  = w3i  + (size_t)b0 * 2304;
        const float* a3r_c  = A3R  + (size_t)b0 * 2304;
        const float* a3i_c  = A3I  + (size_t)b0 * 2304;
        const float* a2r_c  = A2R  + (size_t)b0 * 2304;
        const float* a2i_c  = A2I  + (size_t)b0 * 2304;
        const float* a1r_c  = A1R  + (size_t)b0 * 144;
        const float* a1i_c  = A1I  + (size_t)b0 * 144;
        const float* c7fr_c = C7FR + (size_t)b0 * 784;
        const float* c7fi_c = C7FI + (size_t)b0 * 784;
        const float* c7ar_c = C7AR + (size_t)b0 * 784;
        const float* c7ai_c = C7AI + (size_t)b0 * 784;
        const float* wtr_c  = wtr  + (size_t)b0 * CH * GG;
        const float* wti_c  = wti  + (size_t)b0 * CH * GG;
        float* out_c = out + (size_t)b0 * N1 * N1;

        hipLaunchKernelGGL(dst_stage1, dim3((cb*G*N1 + 255)/256), dim3(256), 0, stream,
                           r_c, SIN, T1D, cb);
        hipLaunchKernelGGL(dst_stage2, dim3(cb*256), dim3(256), 0, stream,
                           T1D, SIN, RHAT);

        // forward strip chain -> corrected A band (CAc)
        hipLaunchKernelGGL(strip_fwd1, dim3(4, cb), dim3(256), 0, stream,
                           RHAT, w1r_c, w1i_c, S1r, S1i);
        hipLaunchKernelGGL(strip_mid, dim3(16, cb), dim3(256), 0, stream,
                           S1r, S1i, w2r_c, w2i_c, S2r, S2i);
        hipLaunchKernelGGL(strip_fin_ca, dim3(16, cb), dim3(256), 0, stream,
                           S2r, S2i, w3r_c, w3i_c, CAc);

        // fused fwd + theta + adjoint conv
        hipLaunchKernelGGL(fused7_kernel, dim3(64*cb), dim3(256), 0, stream,
                           RHAT, wtr_c, wti_c, c7fr_c, c7fi_c, c7ar_c, c7ai_c,
                           CAc, HCc, PTA, cb);

        // adjoint strip chain -> HC border correction
        hipLaunchKernelGGL(strip_adj1_packed, dim3(16, cb), dim3(256), 0, stream,
                           PTA, a3r_c, a3i_c, S1r, S1i);
        hipLaunchKernelGGL(strip_mid, dim3(16, cb), dim3(256), 0, stream,
                           S1r, S1i, a2r_c, a2i_c, S2r, S2i);
        hipLaunchKernelGGL(strip_fin1, dim3(16, cb), dim3(256), 0, stream,
                           S2r, S2i, a1r_c, a1i_c, HCc);

        hipLaunchKernelGGL(fft_stage1, dim3(16*cb), dim3(256), 0, stream,
                           HCc, SIN, Uc);
        hipLaunchKernelGGL(fft_stage2, dim3(cb*N1), dim3(128), 0, stream,
                           Uc, SIN, out_c);
    }
}

// Round 21
// 860.961 us; speedup vs baseline: 1.1327x; 1.0034x over previous
//
#include <hip/hip_runtime.h>
#include <hip/hip_bf16.h>
#include <math.h>

#define NB 32
#define CH 16
#define N1 127
#define G 256
#define GG (G*G)

typedef float v2f __attribute__((ext_vector_type(2)));

// acc(lo=Re,hi=Im) += complex(x) * complex(w);  x=(xr,xi), w=(wr,wi)
#define CFMA(acc, x, w) do { \
  asm("v_pk_fma_f32 %0, %1, %2, %0 op_sel:[0,0,0] op_sel_hi:[0,1,1]" \
      : "+v"(acc) : "v"(x), "v"(w)); \
  asm("v_pk_fma_f32 %0, %1, %2, %0 op_sel:[1,1,0] op_sel_hi:[1,0,1] neg_lo:[0,1,0]" \
      : "+v"(acc) : "v"(x), "v"(w)); \
} while (0)
// acc += complex(x) * conj(t);  t=(c,s):  re += xr c + xi s;  im += xi c - xr s
#define CFMA_CONJ(acc, x, t) do { \
  asm("v_pk_fma_f32 %0, %1, %2, %0 op_sel:[0,0,0] op_sel_hi:[1,0,1]" \
      : "+v"(acc) : "v"(x), "v"(t)); \
  asm("v_pk_fma_f32 %0, %1, %2, %0 op_sel:[1,1,0] op_sel_hi:[0,1,1] neg_hi:[0,1,0]" \
      : "+v"(acc) : "v"(x), "v"(t)); \
} while (0)
// acc += real(x.lo) * complex(w)
#define RFMA_LO(acc, x, w) \
  asm("v_pk_fma_f32 %0, %1, %2, %0 op_sel:[0,0,0] op_sel_hi:[0,1,1]" \
      : "+v"(acc) : "v"(x), "v"(w))
// acc += real(x.hi) * complex(w)
#define RFMA_HI(acc, x, w) \
  asm("v_pk_fma_f32 %0, %1, %2, %0 op_sel:[1,0,0] op_sel_hi:[1,1,1]" \
      : "+v"(acc) : "v"(x), "v"(w))

// ---------------------------------------------------------------------------
__global__ void init_sintab(float* __restrict__ sintab) {
    int t = threadIdx.x;
    sintab[t] = sinf(6.28318530717958647692f * (float)t / 256.0f);
}

// adj(w)[b,a,c,ky,kx] = conj(w[b,c,a,kx,ky])
__global__ __launch_bounds__(256) void prep_adj16(
    const float* __restrict__ wr, const float* __restrict__ wi,
    float* __restrict__ our, float* __restrict__ oui) {
    int idx = blockIdx.x * 256 + threadIdx.x;
    if (idx >= NB*CH*CH*9) return;
    int tap = idx % 9; int t = idx / 9;
    int c = t % CH; t /= CH;
    int a = t % CH; int b = t / CH;
    int ky = tap / 3, kx = tap % 3;
    int src = ((b*CH + c)*CH + a)*9 + kx*3 + ky;
    our[idx] = wr[src];
    oui[idx] = -wi[src];
}

__global__ __launch_bounds__(256) void prep_adj1(
    const float* __restrict__ wr, const float* __restrict__ wi,
    float* __restrict__ our, float* __restrict__ oui) {
    int idx = blockIdx.x * 256 + threadIdx.x;
    if (idx >= NB*CH*9) return;
    int tap = idx % 9; int t = idx / 9;
    int c = t % CH; int b = t / CH;
    int ky = tap / 3, kx = tap % 3;
    int src = (b*CH + c)*9 + kx*3 + ky;
    our[idx] = wr[src];
    oui[idx] = -wi[src];
}

// ---------------------------------------------------------------------------
// Kernel-tap composition: R[t] = sum_{a+b=t} P[a] Q[b]  (complex), contract CM
template<int CO, int CM, int CI, int KP, int KQ>
__global__ __launch_bounds__(256) void compose_k(
    const float* __restrict__ Pr, const float* __restrict__ Pi,
    const float* __restrict__ Qr, const float* __restrict__ Qi,
    float* __restrict__ Rr, float* __restrict__ Ri) {
    constexpr int T = KP + KQ - 1;
    int idx = blockIdx.x * 256 + threadIdx.x;
    if (idx >= NB*CO*CI*T*T) return;
    int txp = idx % T; int t = idx / T;
    int typ = t % T; t /= T;
    int ci = t % CI; t /= CI;
    int co = t % CO; int b = t / CO;
    float ar = 0.f, ai = 0.f;
    for (int m = 0; m < CM; ++m) {
        const float* pr = Pr + (((size_t)b*CO + co)*CM + m)*KP*KP;
        const float* pi = Pi + (((size_t)b*CO + co)*CM + m)*KP*KP;
        const float* qr = Qr + (((size_t)b*CM + m)*CI + ci)*KQ*KQ;
        const float* qi = Qi + (((size_t)b*CM + m)*CI + ci)*KQ*KQ;
        for (int ay = 0; ay < KP; ++ay) {
            int by = typ - ay; if (by < 0 || by >= KQ) continue;
            for (int ax = 0; ax < KP; ++ax) {
                int bx = txp - ax; if (bx < 0 || bx >= KQ) continue;
                float prr = pr[ay*KP+ax], pii = pi[ay*KP+ax];
                float qrr = qr[by*KQ+bx], qii = qi[by*KQ+bx];
                ar += prr*qrr - pii*qii;
                ai += prr*qii + pii*qrr;
            }
        }
    }
    Rr[idx] = ar; Ri[idx] = ai;
}

// ---------------------------------------------------------------------------
// DST stage 1  ((-1)^K folded into sin index)
__global__ __launch_bounds__(256) void dst_stage1(
    const float* __restrict__ r, const float* __restrict__ sintab,
    float* __restrict__ T1, int nb) {
    __shared__ float ss[256];
    ss[threadIdx.x] = sintab[threadIdx.x];
    __syncthreads();
    int idx = blockIdx.x * 256 + threadIdx.x;
    if (idx >= nb*G*N1) return;
    int kk = idx % N1;
    int t = idx / N1;
    int j1 = t & 255; int b = t >> 8;
    const float* rb = r + b * N1 * N1;
    const int j1s = (j1 + 128) & 255;
    float acc = 0.f;
    for (int K = 1; K <= N1; ++K) {
        acc = fmaf(ss[(j1s * K) & 255], rb[(K - 1) * N1 + kk], acc);
    }
    T1[idx] = acc;
}

// DST stage 2
__global__ __launch_bounds__(256) void dst_stage2(
    const float* __restrict__ T1, const float* __restrict__ sintab,
    float* __restrict__ rhat) {
    __shared__ float ss[256];
    ss[threadIdx.x] = sintab[threadIdx.x];
    __syncthreads();
    int idx = blockIdx.x * 256 + threadIdx.x;
    int j2 = idx & 255;
    int t = idx >> 8;
    int j1 = t & 255; int b = t >> 8;
    const float* t1 = T1 + ((size_t)b * G + j1) * N1;
    const int j2s = (j2 + 128) & 255;
    float acc = 0.f;
    for (int kk = 0; kk < N1; ++kk) {
        acc = fmaf(ss[(j2s * (kk + 1)) & 255], t1[kk], acc);
    }
    rhat[idx] = acc * (-4.0f / 65536.0f);
}

// ---------------------------------------------------------------------------
// FUSED conv kernel (champion config + T5 setprio around FMA clusters):
// per 32x32 HC tile, compute composed fwd A on the fly from a 44x44 rhat halo
// (stride 44, 176B rows), patch border from CAc, theta-multiply into single
// sTA buffer, accumulate composed adjoint 7x7.
__global__ __launch_bounds__(256) void fused7_kernel(
    const float* __restrict__ rhat,
    const float* __restrict__ tr, const float* __restrict__ ti,   // [b][16][GG]
    const float* __restrict__ w7fr, const float* __restrict__ w7fi, // [b][16][49]
    const float* __restrict__ w7ar, const float* __restrict__ w7ai, // [b][16][49]
    const float* __restrict__ CAc,  // [b][16][4][2][256][2] corrected A band
    float* __restrict__ HCc, float* __restrict__ PTA, int cb) {
    __shared__ float sR[44*44];        // rhat halo, stride 44
    __shared__ float sTA[38*38*2];     // theta*A staged (single buffer)
    __shared__ float sWf[16*49*2];
    __shared__ float sWa[16*49*2];
    const int lin = blockIdx.x;        // 64*cb blocks
    const int swz = (lin & 7) * (8 * cb) + (lin >> 3);
    const int b = swz >> 6;
    const int tile = swz & 63;
    const int x0 = (tile & 7) * 32;
    const int y0 = (tile >> 3) * 32;
    const int tid = threadIdx.x;
    const bool border = (x0 == 0) | (x0 == 224) | (y0 == 0) | (y0 == 224);
    {
        const float* fr = w7fr + (size_t)b*784; const float* fi = w7fi + (size_t)b*784;
        const float* ar = w7ar + (size_t)b*784; const float* ai = w7ai + (size_t)b*784;
        for (int t = tid; t < 784; t += 256) {
            sWf[2*t] = fr[t]; sWf[2*t+1] = fi[t];
            sWa[2*t] = ar[t]; sWa[2*t+1] = ai[t];
        }
    }
    {
        const float* rb = rhat + (size_t)b * GG;
        for (int t = tid; t < 44*44; t += 256) {
            int ry = t / 44, rx = t - ry*44;
            int gy = y0 - 6 + ry, gx = x0 - 6 + rx;
            bool ok = ((unsigned)gy < G) & ((unsigned)gx < G);
            sR[ry*44 + rx] = ok ? rb[gy*G + gx] : 0.f;
        }
    }
    // A-phase mapping: 190 active threads, each owns 8 consecutive A-halo px
    const bool act = tid < 190;
    const int arow = act ? (tid % 38) : 0;   // A-halo row 0..37
    const int cg   = act ? (tid / 38) : 0;   // col group (8 px)
    // adj mapping: thread owns 4 consecutive outputs in one row
    const int ty = tid >> 3, txi = tid & 7;
    v2f hacc[4];
#pragma unroll
    for (int k = 0; k < 4; ++k) hacc[k] = (v2f){0.f, 0.f};
    const size_t planeT = (size_t)b * 16 * GG;
    __syncthreads();

    for (int ci = 0; ci < 16; ++ci) {
        // ---- theta loads for this ci (issued early, hidden by A compute) --
        float thr[8], thi[8];
        const int pgy = y0 - 3 + arow;
        if (act) {
            const float* trc = tr + planeT + (size_t)ci * GG;
            const float* tic = ti + planeT + (size_t)ci * GG;
#pragma unroll
            for (int k = 0; k < 8; ++k) {
                int acol = 8*cg + k;
                int pgx = x0 - 3 + acol;
                bool ok = (acol < 38) & ((unsigned)pgy < G) & ((unsigned)pgx < G);
                thr[k] = ok ? trc[pgy*G + pgx] : 0.f;
                thi[k] = ok ? tic[pgy*G + pgx] : 0.f;
            }
        }
        // ---- A-halo compute (composed fwd 7x7, real input, pk fma) -------
        v2f aa[8];
#pragma unroll
        for (int k = 0; k < 8; ++k) aa[k] = (v2f){0.f, 0.f};
        if (act) {
            const float* wci = &sWf[ci*49*2];
            __builtin_amdgcn_s_setprio(1);
#pragma unroll
            for (int dy = 0; dy < 7; ++dy) {
                const float* rp = &sR[(arow + dy)*44 + 8*cg];
                v2f fv[8];
#pragma unroll
                for (int q = 0; q < 4; ++q) {
                    const float4 vv = *reinterpret_cast<const float4*>(&rp[4*q]);
                    fv[2*q]   = (v2f){vv.x, vv.y};
                    fv[2*q+1] = (v2f){vv.z, vv.w};
                }
#pragma unroll
                for (int dx = 0; dx < 7; ++dx) {
                    const v2f wv = *reinterpret_cast<const v2f*>(&wci[(dy*7+dx)*2]);
                    const int h = dx >> 1;
                    if ((dx & 1) == 0) {
#pragma unroll
                        for (int m = 0; m < 4; ++m) {
                            RFMA_LO(aa[2*m],   fv[h+m], wv);
                            RFMA_HI(aa[2*m+1], fv[h+m], wv);
                        }
                    } else {
#pragma unroll
                        for (int m = 0; m < 4; ++m) {
                            RFMA_HI(aa[2*m],   fv[h+m],   wv);
                            RFMA_LO(aa[2*m+1], fv[h+m+1], wv);
                        }
                    }
                }
            }
            __builtin_amdgcn_s_setprio(0);
            // patch 2-px border band with corrected A from strip chain
            if (border) {
#pragma unroll
                for (int k = 0; k < 8; ++k) {
                    int acol = 8*cg + k;
                    int gx = x0 - 3 + acol;
                    if (acol < 38 && (unsigned)pgy < G && (unsigned)gx < G) {
                        int s = -1, uu = 0, vv = 0;
                        if (pgy < 2)        { s = 0; uu = pgy;       vv = gx;  }
                        else if (pgy >= 254){ s = 1; uu = pgy - 254; vv = gx;  }
                        else if (gx < 2)    { s = 2; uu = gx;        vv = pgy; }
                        else if (gx >= 254) { s = 3; uu = gx - 254;  vv = pgy; }
                        if (s >= 0) {
                            size_t o = ((((size_t)b*16 + ci)*4 + s)*2 + uu)*256 + vv;
                            aa[k] = *reinterpret_cast<const v2f*>(&CAc[o*2]);
                        }
                    }
                }
            }
        }
        __syncthreads();   // all waves done reading sTA for ci-1
        // ---- theta*A -> sTA (+ PTA extraction on border tiles) -----------
        if (act) {
#pragma unroll
            for (int k = 0; k < 8; ++k) {
                int acol = 8*cg + k;
                if (acol < 38) {
                    float hr = fmaf(aa[k].x, thr[k], -aa[k].y*thi[k]);
                    float hi = fmaf(aa[k].x, thi[k],  aa[k].y*thr[k]);
                    *reinterpret_cast<v2f*>(&sTA[(arow*38 + acol)*2]) = (v2f){hr, hi};
                    if (border) {
                        int gx = x0 - 3 + acol;
                        if ((unsigned)pgy < G && (unsigned)gx < G) {
                            const size_t cbase = ((size_t)b*16 + ci) * 4;
                            if (pgy < 5)    { size_t o = ((cbase+0)*5 + pgy      )*256 + gx;  *reinterpret_cast<v2f*>(&PTA[2*o]) = (v2f){hr,hi}; }
                            if (pgy >= 251) { size_t o = ((cbase+1)*5 + pgy - 251)*256 + gx;  *reinterpret_cast<v2f*>(&PTA[2*o]) = (v2f){hr,hi}; }
                            if (gx < 5)     { size_t o = ((cbase+2)*5 + gx       )*256 + pgy; *reinterpret_cast<v2f*>(&PTA[2*o]) = (v2f){hr,hi}; }
                            if (gx >= 251)  { size_t o = ((cbase+3)*5 + gx - 251 )*256 + pgy; *reinterpret_cast<v2f*>(&PTA[2*o]) = (v2f){hr,hi}; }
                        }
                    }
                }
            }
        }
        __syncthreads();   // sTA ready
        // ---- adjoint accumulate ------------------------------------------
        {
            const float* wci = &sWa[ci*49*2];
            __builtin_amdgcn_s_setprio(1);
#pragma unroll
            for (int dy = 0; dy < 7; ++dy) {
                const float* rowp = &sTA[((ty + dy)*38 + txi*4)*2];
                v2f win[10];
#pragma unroll
                for (int q = 0; q < 5; ++q) {
                    const float4 vv = *reinterpret_cast<const float4*>(&rowp[q*4]);
                    win[2*q]   = (v2f){vv.x, vv.y};
                    win[2*q+1] = (v2f){vv.z, vv.w};
                }
#pragma unroll
                for (int dx = 0; dx < 7; ++dx) {
                    const v2f wv = *reinterpret_cast<const v2f*>(&wci[(dy*7+dx)*2]);
#pragma unroll
                    for (int k = 0; k < 4; ++k)
                        CFMA(hacc[k], win[k+dx], wv);
                }
            }
            __builtin_amdgcn_s_setprio(0);
        }
    }

    const size_t outB = (size_t)b * GG;
    const int oy = y0 + ty, ox = x0 + txi*4;
    float4 o0 = make_float4(hacc[0].x, hacc[0].y, hacc[1].x, hacc[1].y);
    float4 o1 = make_float4(hacc[2].x, hacc[2].y, hacc[3].x, hacc[3].y);
    *reinterpret_cast<float4*>(&HCc[(outB + oy*G + ox)*2])     = o0;
    *reinterpret_cast<float4*>(&HCc[(outB + oy*G + ox)*2 + 4]) = o1;
}

// ---------------------------------------------------------------------------
// Strip machinery. strip s: 0=TOP, 1=BOT, 2=LEF, 3=RIG. [b][ch][s][u:4][v:256].
__device__ __forceinline__ size_t sidx(int b, int ch, int s, int u, int v) {
    return ((((size_t)b*CH + ch)*4 + s)*4 + u)*256 + v;
}
__device__ __forceinline__ void spos(int s, int u, int v, int& y, int& x) {
    y = (s == 0) ? u : (s == 1) ? 252 + u : v;
    x = (s == 2) ? u : (s == 3) ? 252 + u : v;
}

// stage 1 fwd: conv1 (w1, 1->16, real rhat) exact, all u in [0,4)
__global__ __launch_bounds__(256) void strip_fwd1(
    const float* __restrict__ rhat,
    const float* __restrict__ w1r_, const float* __restrict__ w1i_, // [b][16][9]
    float* __restrict__ S1r, float* __restrict__ S1i) {
    __shared__ float sW[16*9*2];
    const int s = blockIdx.x, b = blockIdx.y;
    for (int t = threadIdx.x; t < 144; t += 256) {
        sW[2*t] = w1r_[(size_t)b*144 + t]; sW[2*t+1] = w1i_[(size_t)b*144 + t];
    }
    __syncthreads();
    const int v = threadIdx.x;
    const float* rb = rhat + (size_t)b * GG;
    for (int u = 0; u < 4; ++u) {
        int y, x; spos(s, u, v, y, x);
        float xv[9];
#pragma unroll
        for (int dy = -1; dy <= 1; ++dy)
#pragma unroll
            for (int dx = -1; dx <= 1; ++dx) {
                int gy = y + dy, gx = x + dx;
                bool ok = ((unsigned)gy < G) & ((unsigned)gx < G);
                xv[(dy+1)*3 + dx+1] = ok ? rb[gy*G+gx] : 0.f;
            }
#pragma unroll
        for (int co = 0; co < 16; ++co) {
            float ar = 0.f, ai = 0.f;
#pragma unroll
            for (int tap = 0; tap < 9; ++tap) {
                ar = fmaf(xv[tap], sW[(co*9+tap)*2], ar);
                ai = fmaf(xv[tap], sW[(co*9+tap)*2+1], ai);
            }
            S1r[sidx(b, co, s, u, v)] = ar;
            S1i[sidx(b, co, s, u, v)] = ai;
        }
    }
}

// stage 1 adj (packed): a3-conv on packed theta.*A bands. u in [0,4). pk_fma.
__global__ __launch_bounds__(256) void strip_adj1_packed(
    const float* __restrict__ PTA,   // [b][ci][4][5][256][2]
    const float* __restrict__ wr_, const float* __restrict__ wi_, // [b][16][16][9]
    float* __restrict__ S1r, float* __restrict__ S1i) {
    __shared__ float sW[16*16*9*2];
    const int s = blockIdx.x >> 2, vt = blockIdx.x & 3, b = blockIdx.y;
    for (int t = threadIdx.x; t < 2304; t += 256) {
        sW[2*t] = wr_[(size_t)b*2304 + t]; sW[2*t+1] = wi_[(size_t)b*2304 + t];
    }
    __syncthreads();
    const int v = vt * 64 + (threadIdx.x & 63);
    const int u = threadIdx.x >> 6;           // 0..3
    const int off = (s == 1 || s == 3) ? 1 : 0;
    v2f acc[16];
#pragma unroll
    for (int co = 0; co < 16; ++co) acc[co] = (v2f){0.f, 0.f};
    for (int ci = 0; ci < 16; ++ci) {
        const float* base = PTA + ((((size_t)b*16 + ci)*4 + s)*5) * 512;
        v2f n2[9];
#pragma unroll
        for (int dy = -1; dy <= 1; ++dy)
#pragma unroll
            for (int dx = -1; dx <= 1; ++dx) {
                int pu = (s < 2) ? (u + off + dy) : (u + off + dx);
                int vp = (s < 2) ? (v + dx) : (v + dy);
                v2f val = (v2f){0.f, 0.f};
                if (((unsigned)pu < 5u) & ((unsigned)vp < 256u))
                    val = *reinterpret_cast<const v2f*>(&base[(pu*256 + vp)*2]);
                n2[(dy+1)*3+dx+1] = val;
            }
#pragma unroll
        for (int co = 0; co < 16; ++co)
#pragma unroll
            for (int tap = 0; tap < 9; ++tap) {
                const v2f wv = *reinterpret_cast<const v2f*>(&sW[((co*16+ci)*9+tap)*2]);
                CFMA(acc[co], n2[tap], wv);
            }
    }
#pragma unroll
    for (int co = 0; co < 16; ++co) {
        S1r[sidx(b, co, s, u, v)] = acc[co].x;
        S1i[sidx(b, co, s, u, v)] = acc[co].y;
    }
}

// stage 2: 16->16 conv strips->strips, u in [u0, u0+3). grid (16, cb). pk_fma.
__global__ __launch_bounds__(256) void strip_mid(
    const float* __restrict__ Ar, const float* __restrict__ Ai,
    const float* __restrict__ wr_, const float* __restrict__ wi_, // [b][16][16][9]
    float* __restrict__ Br, float* __restrict__ Bi) {
    __shared__ float sW[16*16*9*2];
    const int s = blockIdx.x >> 2, vt = blockIdx.x & 3, b = blockIdx.y;
    for (int t = threadIdx.x; t < 2304; t += 256) {
        sW[2*t] = wr_[(size_t)b*2304 + t]; sW[2*t+1] = wi_[(size_t)b*2304 + t];
    }
    __syncthreads();
    const int v = vt * 64 + (threadIdx.x & 63);
    const int uslot = threadIdx.x >> 6;
    if (uslot >= 3) return;
    const int u0 = (s == 1 || s == 3) ? 1 : 0;
    const int u = u0 + uslot;
    int y, x; spos(s, u, v, y, x);
    v2f acc[16];
#pragma unroll
    for (int co = 0; co < 16; ++co) acc[co] = (v2f){0.f, 0.f};
    for (int ci = 0; ci < 16; ++ci) {
        v2f n2[9];
#pragma unroll
        for (int dy = -1; dy <= 1; ++dy)
#pragma unroll
            for (int dx = -1; dx <= 1; ++dx) {
                int gy = y + dy, gx = x + dx;
                v2f val = (v2f){0.f, 0.f};
                if (((unsigned)gy < G) & ((unsigned)gx < G)) {
                    int up = (s < 2) ? u + dy : u + dx;
                    int vp = (s < 2) ? v + dx : v + dy;
                    size_t ix = sidx(b, ci, s, up, vp);
                    val.x = Ar[ix]; val.y = Ai[ix];
                }
                n2[(dy+1)*3+dx+1] = val;
            }
#pragma unroll
        for (int co = 0; co < 16; ++co)
#pragma unroll
            for (int tap = 0; tap < 9; ++tap) {
                const v2f wv = *reinterpret_cast<const v2f*>(&sW[((co*16+ci)*9+tap)*2]);
                CFMA(acc[co], n2[tap], wv);
            }
    }
#pragma unroll
    for (int co = 0; co < 16; ++co) {
        Br[sidx(b, co, s, u, v)] = acc[co].x;
        Bi[sidx(b, co, s, u, v)] = acc[co].y;
    }
}

// stage 3 fwd variant: 16 ch from strips -> compact corrected-A band CAc.
__global__ __launch_bounds__(256) void strip_fin_ca(
    const float* __restrict__ Ar, const float* __restrict__ Ai,
    const float* __restrict__ wr_, const float* __restrict__ wi_, // [b][16][16][9]
    float* __restrict__ CAc) {
    __shared__ float sW[16*16*9*2];
    const int s = blockIdx.x >> 2, vt = blockIdx.x & 3, b = blockIdx.y;
    for (int t = threadIdx.x; t < 2304; t += 256) {
        sW[2*t] = wr_[(size_t)b*2304 + t]; sW[2*t+1] = wi_[(size_t)b*2304 + t];
    }
    __syncthreads();
    const int v = vt * 64 + (threadIdx.x & 63);
    const int uslot = threadIdx.x >> 6;
    if (uslot >= 2) return;
    const int u0 = (s == 1 || s == 3) ? 2 : 0;
    const int u = u0 + uslot;
    int y, x; spos(s, u, v, y, x);
    v2f acc[16];
#pragma unroll
    for (int co = 0; co < 16; ++co) acc[co] = (v2f){0.f, 0.f};
    for (int ci = 0; ci < 16; ++ci) {
        v2f n2[9];
#pragma unroll
        for (int dy = -1; dy <= 1; ++dy)
#pragma unroll
            for (int dx = -1; dx <= 1; ++dx) {
                int gy = y + dy, gx = x + dx;
                v2f val = (v2f){0.f, 0.f};
                if (((unsigned)gy < G) & ((unsigned)gx < G)) {
                    int up = (s < 2) ? u + dy : u + dx;
                    int vp = (s < 2) ? v + dx : v + dy;
                    size_t ix = sidx(b, ci, s, up, vp);
                    val.x = Ar[ix]; val.y = Ai[ix];
                }
                n2[(dy+1)*3+dx+1] = val;
            }
#pragma unroll
        for (int co = 0; co < 16; ++co)
#pragma unroll
            for (int tap = 0; tap < 9; ++tap) {
                const v2f wv = *reinterpret_cast<const v2f*>(&sW[((co*16+ci)*9+tap)*2]);
                CFMA(acc[co], n2[tap], wv);
            }
    }
#pragma unroll
    for (int co = 0; co < 16; ++co) {
        size_t o = ((((size_t)b*16 + co)*4 + s)*2 + uslot)*256 + v;
        *reinterpret_cast<v2f*>(&CAc[o*2]) = acc[co];
    }
}

// stage 3 adj: 1 ch from strips -> overwrite band in interleaved HCc.
__global__ __launch_bounds__(256) void strip_fin1(
    const float* __restrict__ Ar, const float* __restrict__ Ai,
    const float* __restrict__ wr_, const float* __restrict__ wi_, // [b][1][16][9]
    float* __restrict__ Oc) {
    __shared__ float sW[16*9*2];
    const int s = blockIdx.x >> 2, vt = blockIdx.x & 3, b = blockIdx.y;
    for (int t = threadIdx.x; t < 144; t += 256) {
        sW[2*t] = wr_[(size_t)b*144 + t]; sW[2*t+1] = wi_[(size_t)b*144 + t];
    }
    __syncthreads();
    const int v = vt * 64 + (threadIdx.x & 63);
    const int uslot = threadIdx.x >> 6;
    if (uslot >= 2) return;
    const int u0 = (s == 1 || s == 3) ? 2 : 0;
    const int u = u0 + uslot;
    int y, x; spos(s, u, v, y, x);
    v2f acc = (v2f){0.f, 0.f};
    for (int ci = 0; ci < 16; ++ci) {
#pragma unroll
        for (int dy = -1; dy <= 1; ++dy)
#pragma unroll
            for (int dx = -1; dx <= 1; ++dx) {
                int gy = y + dy, gx = x + dx;
                v2f val = (v2f){0.f, 0.f};
                if (((unsigned)gy < G) & ((unsigned)gx < G)) {
                    int up = (s < 2) ? u + dy : u + dx;
                    int vp = (s < 2) ? v + dx : v + dy;
                    size_t ix = sidx(b, ci, s, up, vp);
                    val.x = Ar[ix]; val.y = Ai[ix];
                }
                const v2f wv = *reinterpret_cast<const v2f*>(&sW[(ci*9 + (dy+1)*3 + dx+1)*2]);
                CFMA(acc, val, wv);
            }
    }
    *reinterpret_cast<v2f*>(&Oc[(((size_t)b)*GG + y*G + x)*2]) = acc;
}

// ---------------------------------------------------------------------------
// FFT stage 1 (tiled GEMM): U[b][k1][j2] = sum_j1 HC[b][j1][j2] e^{-2pi i k1 j1/256}.
__global__ __launch_bounds__(256) void fft_stage1(
    const float* __restrict__ HCc, const float* __restrict__ sintab,
    float* __restrict__ Uc) {
    __shared__ v2f sHC[64][16];
    __shared__ v2f sTW[256];
    const int jt = blockIdx.x & 15;
    const int b  = blockIdx.x >> 4;
    const int tid = threadIdx.x;
    {
        int ph = tid;
        sTW[tid] = (v2f){sintab[(ph + 64) & 255], sintab[ph]};  // (c, s)
    }
    const int j2c = tid & 15;
    const int kg  = tid >> 4;           // 0..15
    const int j2  = jt * 16 + j2c;
    const float* hc = HCc + ((size_t)b * GG + j2) * 2;
    v2f acc[8];
    int ph[8];
#pragma unroll
    for (int i = 0; i < 8; ++i) { acc[i] = (v2f){0.f, 0.f}; ph[i] = 0; }
    for (int c = 0; c < 4; ++c) {
        __syncthreads();
#pragma unroll
        for (int q = 0; q < 4; ++q) {
            int jj = 16*q + kg;
            sHC[jj][j2c] = *reinterpret_cast<const v2f*>(&hc[((size_t)(c*64 + jj) * G) * 2]);
        }
        __syncthreads();
#pragma unroll 8
        for (int jj = 0; jj < 64; ++jj) {
            const v2f x = sHC[jj][j2c];
#pragma unroll
            for (int i = 0; i < 8; ++i) {
                const v2f t = sTW[ph[i]];
                CFMA_CONJ(acc[i], x, t);
                ph[i] = (ph[i] + kg + 16*i) & 255;
            }
        }
    }
#pragma unroll
    for (int i = 0; i < 8; ++i) {
        int k1 = kg + 16*i;
        if (k1 < N1)
            *reinterpret_cast<v2f*>(&Uc[(((size_t)b * N1 + k1) * G + j2) * 2]) = acc[i];
    }
}

// FFT stage 2 (Re-only, v2f twiddle table, incremental phase):
// e[b][k1][k2] = (-1)^{k1+k2} sum_j2 ( Ur c + Ui s ),  (c,s) = tw(k2*j2).
__global__ __launch_bounds__(128) void fft_stage2(
    const float* __restrict__ Uc, const float* __restrict__ sintab,
    float* __restrict__ out) {
    __shared__ v2f sU[256];
    __shared__ v2f sT[256];
    const int k1 = blockIdx.x % N1;
    const int b  = blockIdx.x / N1;
    const int tid = threadIdx.x;
    const float* uc = Uc + ((size_t)b * N1 + k1) * G * 2;
    sU[tid]       = *reinterpret_cast<const v2f*>(&uc[tid * 2]);
    sU[tid + 128] = *reinterpret_cast<const v2f*>(&uc[(tid + 128) * 2]);
    sT[tid]       = (v2f){sintab[(tid + 64) & 255],  sintab[tid]};        // (c,s)
    sT[tid + 128] = (v2f){sintab[(tid + 192) & 255], sintab[tid + 128]};
    __syncthreads();
    if (tid >= N1) return;
    const int k2 = tid;
    float acc = 0.f;
    int ph = 0;
#pragma unroll 4
    for (int j2 = 0; j2 < G; ++j2) {
        const v2f u = sU[j2];
        const v2f t = sT[ph];
        acc = fmaf(u.x, t.x, fmaf(u.y, t.y, acc));
        ph = (ph + k2) & 255;
    }
    float res = ((k1 + k2) & 1) ? -acc : acc;
    out[((size_t)b * N1 + k1) * N1 + k2] = res;
}

// ---------------------------------------------------------------------------
extern "C" void kernel_launch(void* const* d_in, const int* in_sizes, int n_in,
                              void* d_out, int out_size, void* d_ws, size_t ws_size,
                              hipStream_t stream) {
    const float* r   = (const float*)d_in[0];
    const float* w1r = (const float*)d_in[1];
    const float* w1i = (const float*)d_in[2];
    const float* w2r = (const float*)d_in[3];
    const float* w2i = (const float*)d_in[4];
    const float* w3r = (const float*)d_in[5];
    const float* w3i = (const float*)d_in[6];
    const float* wtr = (const float*)d_in[7];
    const float* wti = (const float*)d_in[8];
    float* out = (float*)d_out;

    float* ws = (float*)d_ws;
    const size_t g = (size_t)GG;

    // ---- fixed region ---------------------------------------------------
    const size_t SZ16 = (size_t)NB*CH*CH*9;
    const size_t SZ1  = (size_t)NB*CH*9;
    const size_t SZ5  = (size_t)NB*16*25;
    const size_t SZ7  = (size_t)NB*16*49;
    float* p = ws;
    float* SIN  = p; p += 1024;
    float* A3R = p; p += SZ16;  float* A3I = p; p += SZ16;
    float* A2R = p; p += SZ16;  float* A2I = p; p += SZ16;
    float* A1R = p; p += SZ1;   float* A1I = p; p += SZ1;
    float* C5R = p; p += SZ5;   float* C5I = p; p += SZ5;
    float* C7FR = p; p += SZ7;  float* C7FI = p; p += SZ7;
    float* Q5R = p; p += SZ5;   float* Q5I = p; p += SZ5;
    float* C7AR = p; p += SZ7;  float* C7AI = p; p += SZ7;
    const size_t extraFloats = (size_t)(p - ws);

    // ---- chunking: per-sample floats ------------------------------------
    const size_t sampFloats = g + 2*g + 2*g + 2*g + (5*g)/2 + g/2;  // 10g
    size_t availFloats = ws_size / 4;
    long long usable = (long long)availFloats - (long long)extraFloats;
    int cbm = 1;
    if (usable > 0) {
        long long c = usable / (long long)sampFloats;
        cbm = (int)(c < 1 ? 1 : (c > NB ? NB : c));
    }

    float* base = ws + extraFloats;
    float* RHAT = base;                            // [cb][GG]
    float* S1r  = RHAT + (size_t)cbm*g;
    float* S1i  = S1r + (size_t)cbm*g;
    float* S2r  = S1i + (size_t)cbm*g;
    float* S2i  = S2r + (size_t)cbm*g;
    float* HCc  = S2i + (size_t)cbm*g;             // [cb][GG][2]
    float* PTA  = HCc + (size_t)cbm*2*g;           // [cb][16][4][5][256][2] = 2.5g
    float* CAc  = PTA + (size_t)cbm*((5*g)/2);     // [cb][16][4][2][256][2] = 0.5g
    float* T1D  = S2r;                             // overlay (dead before strip_mid)
    float* Uc   = S1r;                             // overlay (dead before fft1)

    // ---- one-time prep --------------------------------------------------
    hipLaunchKernelGGL(init_sintab, dim3(1), dim3(256), 0, stream, SIN);
    hipLaunchKernelGGL(prep_adj16, dim3((unsigned)((SZ16+255)/256)), dim3(256), 0, stream,
                       w3r, w3i, A3R, A3I);
    hipLaunchKernelGGL(prep_adj16, dim3((unsigned)((SZ16+255)/256)), dim3(256), 0, stream,
                       w2r, w2i, A2R, A2I);
    hipLaunchKernelGGL(prep_adj1,  dim3((unsigned)((SZ1+255)/256)),  dim3(256), 0, stream,
                       w1r, w1i, A1R, A1I);
    hipLaunchKernelGGL((compose_k<16,16,1,3,3>), dim3((unsigned)((NB*16*25+255)/256)), dim3(256),
                       0, stream, w2r, w2i, w1r, w1i, C5R, C5I);
    hipLaunchKernelGGL((compose_k<16,16,1,3,5>), dim3((unsigned)((NB*16*49+255)/256)), dim3(256),
                       0, stream, w3r, w3i, C5R, C5I, C7FR, C7FI);
    hipLaunchKernelGGL((compose_k<1,16,16,3,3>), dim3((unsigned)((NB*16*25+255)/256)), dim3(256),
                       0, stream, A1R, A1I, A2R, A2I, Q5R, Q5I);
    hipLaunchKernelGGL((compose_k<1,16,16,5,3>), dim3((unsigned)((NB*16*49+255)/256)), dim3(256),
                       0, stream, Q5R, Q5I, A3R, A3I, C7AR, C7AI);

    // ---- per-chunk pipeline --------------------------------------------
    for (int b0 = 0; b0 < NB; b0 += cbm) {
        const int cb = (NB - b0) < cbm ? (NB - b0) : cbm;

        const float* r_c    = r    + (size_t)b0 * N1 * N1;
        const float* w1r_c  = w1r  + (size_t)b0 * 144;
        const float* w1i_c  = w1i  + (size_t)b0 * 144;
        const float* w2r_c  = w2r  + (size_t)b0 * 2304;
        const float* w2i_c  = w2i  + (size_t)b0 * 2304;
        const float* w3r_c  = w3r  + (size_t)b0 * 2304;
        const float* w3i_c  = w3i  + (size_t)b0 * 2304;
        const float* a3r_c  = A3R  + (size_t)b0 * 2304;
        const float* a3i_c  = A3I  + (size_t)b0 * 2304;
        const float* a2r_c  = A2R  + (size_t)b0 * 2304;
        const float* a2i_c  = A2I  + (size_t)b0 * 2304;
        const float* a1r_c  = A1R  + (size_t)b0 * 144;
        const float* a1i_c  = A1I  + (size_t)b0 * 144;
        const float* c7fr_c = C7FR + (size_t)b0 * 784;
        const float* c7fi_c = C7FI + (size_t)b0 * 784;
        const float* c7ar_c = C7AR + (size_t)b0 * 784;
        const float* c7ai_c = C7AI + (size_t)b0 * 784;
        const float* wtr_c  = wtr  + (size_t)b0 * CH * GG;
        const float* wti_c  = wti  + (size_t)b0 * CH * GG;
        float* out_c = out + (size_t)b0 * N1 * N1;

        hipLaunchKernelGGL(dst_stage1, dim3((cb*G*N1 + 255)/256), dim3(256), 0, stream,
                           r_c, SIN, T1D, cb);
        hipLaunchKernelGGL(dst_stage2, dim3(cb*256), dim3(256), 0, stream,
                           T1D, SIN, RHAT);

        // forward strip chain -> corrected A band (CAc)
        hipLaunchKernelGGL(strip_fwd1, dim3(4, cb), dim3(256), 0, stream,
                           RHAT, w1r_c, w1i_c, S1r, S1i);
        hipLaunchKernelGGL(strip_mid, dim3(16, cb), dim3(256), 0, stream,
                           S1r, S1i, w2r_c, w2i_c, S2r, S2i);
        hipLaunchKernelGGL(strip_fin_ca, dim3(16, cb), dim3(256), 0, stream,
                           S2r, S2i, w3r_c, w3i_c, CAc);

        // fused fwd + theta + adjoint conv
        hipLaunchKernelGGL(fused7_kernel, dim3(64*cb), dim3(256), 0, stream,
                           RHAT, wtr_c, wti_c, c7fr_c, c7fi_c, c7ar_c, c7ai_c,
                           CAc, HCc, PTA, cb);

        // adjoint strip chain -> HC border correction
        hipLaunchKernelGGL(strip_adj1_packed, dim3(16, cb), dim3(256), 0, stream,
                           PTA, a3r_c, a3i_c, S1r, S1i);
        hipLaunchKernelGGL(strip_mid, dim3(16, cb), dim3(256), 0, stream,
                           S1r, S1i, a2r_c, a2i_c, S2r, S2i);
        hipLaunchKernelGGL(strip_fin1, dim3(16, cb), dim3(256), 0, stream,
                           S2r, S2i, a1r_c, a1i_c, HCc);

        hipLaunchKernelGGL(fft_stage1, dim3(16*cb), dim3(256), 0, stream,
                           HCc, SIN, Uc);
        hipLaunchKernelGGL(fft_stage2, dim3(cb*N1), dim3(128), 0, stream,
                           Uc, SIN, out_c);
    }
}